// Round 6
// baseline (594.467 us; speedup 1.0000x reference)
//
#include <hip/hip_runtime.h>

#define N_NODES 50000
#define N_EDGES 600000
#define IN_DIM 256
#define HID 128
#define OUT_DIM 10
#define BN_EPS 1e-5f

typedef unsigned int uint32;
typedef __attribute__((ext_vector_type(8))) short short8;   // 8 bf16 = 4 VGPRs
typedef __attribute__((ext_vector_type(4))) float float4v;  // MFMA acc

__device__ __forceinline__ unsigned short f2bf_rne(float f) {
    uint32 u = __float_as_uint(f);
    u += 0x7FFF + ((u >> 16) & 1);          // round-to-nearest-even
    return (unsigned short)(u >> 16);
}
__device__ __forceinline__ float bf_lo(uint32 v) { return __uint_as_float(v << 16); }
__device__ __forceinline__ float bf_hi(uint32 v) { return __uint_as_float(v & 0xFFFF0000u); }

// ---------------- edge preprocessing: CSR by dst (no prefix scan needed) ----------------

__global__ void count_kernel(const int* __restrict__ dst, int* __restrict__ cnt) {
    int e = blockIdx.x * blockDim.x + threadIdx.x;
    if (e < N_EDGES) atomicAdd(&cnt[dst[e]], 1);
}

// Wave-64 inclusive scan of counts, one atomicAdd on a global cursor per wave.
__global__ __launch_bounds__(256) void assign_kernel(const int* __restrict__ cnt,
                                                     int* __restrict__ row_start,
                                                     int* __restrict__ fill_ptr,
                                                     float* __restrict__ dinv,
                                                     int* __restrict__ cursor) {
    int i = blockIdx.x * blockDim.x + threadIdx.x;
    int c = (i < N_NODES) ? cnt[i] : 0;
    int lane = threadIdx.x & 63;
    int v = c;
    #pragma unroll
    for (int off = 1; off < 64; off <<= 1) {
        int t = __shfl_up(v, off, 64);
        if (lane >= off) v += t;
    }
    int waveTotal = __shfl(v, 63, 64);
    int base = 0;
    if (lane == 63) base = atomicAdd(cursor, waveTotal);
    base = __shfl(base, 63, 64);
    if (i < N_NODES) {
        int start = base + v - c;
        row_start[i] = start;
        fill_ptr[i] = start;
        dinv[i] = rsqrtf((float)c + 1.0f);   // +1 self-loop
    }
}

__global__ void fill_kernel(const int* __restrict__ src, const int* __restrict__ dst,
                            int* __restrict__ fill_ptr, int* __restrict__ col_src) {
    int e = blockIdx.x * blockDim.x + threadIdx.x;
    if (e < N_EDGES) {
        int d = dst[e];
        int p = atomicAdd(&fill_ptr[d], 1);
        col_src[p] = src[e];
    }
}

// ---------------- weight pre-pack into MFMA B-fragment layout ----------------
// For each layer: P[((kt*8+nt)*64+lane)*8+j] = bf16( W[kt*32+(lane>>4)*8+j][nt*16+(lane&15)] )

__global__ void pack_w_kernel(const float* __restrict__ W, unsigned short* __restrict__ P,
                              int K, int per, int total) {
    int idx = blockIdx.x * blockDim.x + threadIdx.x;
    if (idx >= total) return;
    int layer = idx / per;
    int r = idx - layer * per;
    int lane = r & 63;
    int nt = (r >> 6) & 7;
    int kt = r >> 9;
    int n = nt * 16 + (lane & 15);
    int kbase = kt * 32 + (lane >> 4) * 8;
    const float* Wl = W + (size_t)layer * K * HID;
    unsigned short* dstp = P + (size_t)idx * 8;
    #pragma unroll
    for (int j = 0; j < 8; ++j) dstp[j] = f2bf_rne(Wl[(size_t)(kbase + j) * HID + n]);
}

// ---------------- MFMA bf16 GEMM: out[M,128] = (A[M,K]@W) * rowscale (+bias)(+relu) ----------------
// block 256 = 4 waves; tile 64 rows x 128 cols. A staged in LDS, stride 40 shorts (2-way bank alias, free).
// INBF16: A is bf16 row-major [M][K]; else fp32 (converted in staging).
// MFMA mappings (m89-verified): A[m=lane&15][k=quad*8+j]; D: col=lane&15, row=quad*4+reg.

template <int K, int INBF16, int RELU, int OUTBF16>
__global__ __launch_bounds__(256) void gemm_mfma(const void* __restrict__ A_v,
                                                 const unsigned short* __restrict__ PB,
                                                 const float* __restrict__ bias,
                                                 const float* __restrict__ rowscale,
                                                 void* __restrict__ out_v, int M) {
    __shared__ unsigned short As[64 * 40];
    int tid = threadIdx.x;
    int w = tid >> 6, lane = tid & 63;
    int mrow = lane & 15, quad = lane >> 4;
    int m0 = blockIdx.x * 64;

    float4v acc[8];
    #pragma unroll
    for (int nt = 0; nt < 8; ++nt)
        #pragma unroll
        for (int i = 0; i < 4; ++i) acc[nt][i] = 0.f;

    int r = tid >> 2;        // 0..63: staging row
    int cq = tid & 3;        // col quarter (8 elements)

    for (int kt = 0; kt < K / 32; ++kt) {
        short8 pk;
        if (m0 + r < M) {
            if (INBF16) {
                pk = *(const short8*)((const unsigned short*)A_v + (size_t)(m0 + r) * K + kt * 32 + cq * 8);
            } else {
                const float* srcp = (const float*)A_v + (size_t)(m0 + r) * K + kt * 32 + cq * 8;
                float4 a0 = *(const float4*)(srcp);
                float4 a1 = *(const float4*)(srcp + 4);
                pk[0] = (short)f2bf_rne(a0.x); pk[1] = (short)f2bf_rne(a0.y);
                pk[2] = (short)f2bf_rne(a0.z); pk[3] = (short)f2bf_rne(a0.w);
                pk[4] = (short)f2bf_rne(a1.x); pk[5] = (short)f2bf_rne(a1.y);
                pk[6] = (short)f2bf_rne(a1.z); pk[7] = (short)f2bf_rne(a1.w);
            }
        } else {
            #pragma unroll
            for (int j = 0; j < 8; ++j) pk[j] = 0;
        }
        __syncthreads();                       // protect previous iteration's reads
        *(short8*)&As[r * 40 + cq * 8] = pk;
        __syncthreads();

        short8 afrag = *(const short8*)&As[(w * 16 + mrow) * 40 + quad * 8];

        const unsigned short* pb = PB + ((size_t)(kt * 8) * 64 + lane) * 8;
        #pragma unroll
        for (int nt = 0; nt < 8; ++nt) {
            short8 bfrag = *(const short8*)(pb + (size_t)nt * 64 * 8);
            acc[nt] = __builtin_amdgcn_mfma_f32_16x16x32_bf16(afrag, bfrag, acc[nt], 0, 0, 0);
        }
    }

    // epilogue: row = m0 + w*16 + quad*4 + reg, col = nt*16 + mrow
    int rowbase = m0 + w * 16 + quad * 4;
    float rs[4];
    #pragma unroll
    for (int reg = 0; reg < 4; ++reg) {
        int row = rowbase + reg;
        rs[reg] = (rowscale && row < M) ? rowscale[row] : 1.0f;
    }
    #pragma unroll
    for (int nt = 0; nt < 8; ++nt) {
        int col = nt * 16 + mrow;
        float bv = bias ? bias[col] : 0.f;
        #pragma unroll
        for (int reg = 0; reg < 4; ++reg) {
            int row = rowbase + reg;
            if (row < M) {
                float o = acc[nt][reg] * rs[reg] + bv;
                if (RELU) o = fmaxf(o, 0.f);
                if (OUTBF16)
                    ((unsigned short*)out_v)[(size_t)row * HID + col] = f2bf_rne(o);
                else
                    ((float*)out_v)[(size_t)row * HID + col] = o;
            }
        }
    }
}

// ---------------- fused CSR pull aggregation + BN column stats ----------------
// B rows: 128 bf16 (256 B), pre-scaled by dinv[row].
// C[n][f] = dinv[n]*(B[n][f] + sum_e B[src_e][f]) + bc[f]
// block (64,4) = 4 waves; wave = one node; half-wave per edge (uint2 = 4 bf16 per lane).
// grid 3125, each wave-slot handles 4 nodes (chunk-strided). Per-block column sums -> atomicAdd.

__global__ __launch_bounds__(256) void agg_stats_kernel(const uint2* __restrict__ B2,   // [N][32]
                                                        const float* __restrict__ dinv,
                                                        const int* __restrict__ row_start,
                                                        const int* __restrict__ cnt,
                                                        const int* __restrict__ col_src,
                                                        const float* __restrict__ bc,
                                                        float* __restrict__ C,
                                                        float* __restrict__ colsum,
                                                        float* __restrict__ colsumsq) {
    __shared__ float shs[4][128];
    __shared__ float shq[4][128];
    int lane = threadIdx.x;            // 0..63
    int ty = threadIdx.y;              // 0..3
    int half = lane >> 5;              // 0/1: even/odd edges
    int hl = lane & 31;                // feature group: f = hl*4 .. hl*4+3

    float4 bcv = ((const float4*)bc)[hl];
    float ss0 = 0.f, ss1 = 0.f, ss2 = 0.f, ss3 = 0.f;
    float sq0 = 0.f, sq1 = 0.f, sq2 = 0.f, sq3 = 0.f;

    #pragma unroll
    for (int chunk = 0; chunk < 4; ++chunk) {
        int n = blockIdx.x * 4 + ty + chunk * 12500;

        float a0, a1, a2, a3;
        if (half == 0) {
            uint2 v = B2[(size_t)n * 32 + hl];      // self term
            a0 = bf_lo(v.x); a1 = bf_hi(v.x); a2 = bf_lo(v.y); a3 = bf_hi(v.y);
        } else { a0 = a1 = a2 = a3 = 0.f; }

        int beg = row_start[n];
        int cn = cnt[n];
        int pairs = cn >> 1;
        int e = beg + half;
        int i = 0;
        for (; i + 2 <= pairs; i += 2) {            // 4 edges in flight per wave
            int s0 = col_src[e];
            int s1 = col_src[e + 2];
            uint2 v0 = B2[(size_t)s0 * 32 + hl];
            uint2 v1 = B2[(size_t)s1 * 32 + hl];
            a0 += bf_lo(v0.x); a1 += bf_hi(v0.x); a2 += bf_lo(v0.y); a3 += bf_hi(v0.y);
            a0 += bf_lo(v1.x); a1 += bf_hi(v1.x); a2 += bf_lo(v1.y); a3 += bf_hi(v1.y);
            e += 4;
        }
        for (; i < pairs; ++i) {
            int s = col_src[e];
            uint2 v = B2[(size_t)s * 32 + hl];
            a0 += bf_lo(v.x); a1 += bf_hi(v.x); a2 += bf_lo(v.y); a3 += bf_hi(v.y);
            e += 2;
        }
        if ((cn & 1) && half == 0) {                // leftover odd edge
            int s = col_src[beg + cn - 1];
            uint2 v = B2[(size_t)s * 32 + hl];
            a0 += bf_lo(v.x); a1 += bf_hi(v.x); a2 += bf_lo(v.y); a3 += bf_hi(v.y);
        }

        a0 += __shfl_xor(a0, 32, 64);
        a1 += __shfl_xor(a1, 32, 64);
        a2 += __shfl_xor(a2, 32, 64);
        a3 += __shfl_xor(a3, 32, 64);

        float di = dinv[n];
        float o0 = a0 * di + bcv.x;
        float o1 = a1 * di + bcv.y;
        float o2 = a2 * di + bcv.z;
        float o3 = a3 * di + bcv.w;
        if (half == 0) {
            ((float4*)C)[(size_t)n * 32 + hl] = make_float4(o0, o1, o2, o3);
            ss0 += o0; ss1 += o1; ss2 += o2; ss3 += o3;
            sq0 += o0 * o0; sq1 += o1 * o1; sq2 += o2 * o2; sq3 += o3 * o3;
        }
    }

    if (half == 0) {
        *(float4*)&shs[ty][hl * 4] = make_float4(ss0, ss1, ss2, ss3);
        *(float4*)&shq[ty][hl * 4] = make_float4(sq0, sq1, sq2, sq3);
    }
    __syncthreads();
    int t = ty * 64 + lane;
    if (t < 128) {
        float s = shs[0][t] + shs[1][t] + shs[2][t] + shs[3][t];
        float q = shq[0][t] + shq[1][t] + shq[2][t] + shq[3][t];
        atomicAdd(&colsum[t], s);
        atomicAdd(&colsumsq[t], q);
    }
}

// ---------------- BN finalize / apply ----------------

__global__ void finalize_bn(const float* __restrict__ colsum, const float* __restrict__ colsumsq,
                            const float* __restrict__ gamma, const float* __restrict__ beta,
                            float* __restrict__ scale, float* __restrict__ shift) {
    int f = threadIdx.x;
    float mu = colsum[f] * (1.0f / N_NODES);
    float var = colsumsq[f] * (1.0f / N_NODES) - mu * mu;
    float rstd = rsqrtf(var + BN_EPS);
    float sc = rstd * gamma[f];
    scale[f] = sc;
    shift[f] = beta[f] - mu * sc;
}

// h = relu(C*scale+shift) (+A residual); writes A fp32, optionally A16 bf16 (next gemm input)
template <int RES, int W16>
__global__ __launch_bounds__(256) void apply_bn(const float* __restrict__ C,
                                                const float* __restrict__ scale,
                                                const float* __restrict__ shift,
                                                float* __restrict__ A,
                                                unsigned short* __restrict__ A16) {
    int idx = blockIdx.x * blockDim.x + threadIdx.x;   // float4 index
    const int total = N_NODES * HID / 4;
    if (idx >= total) return;
    int fq = idx & 31;                                  // 32 float4 per row
    float4 c = ((const float4*)C)[idx];
    float4 sc = ((const float4*)scale)[fq];
    float4 sh = ((const float4*)shift)[fq];
    float4 h;
    h.x = fmaxf(c.x * sc.x + sh.x, 0.f);
    h.y = fmaxf(c.y * sc.y + sh.y, 0.f);
    h.z = fmaxf(c.z * sc.z + sh.z, 0.f);
    h.w = fmaxf(c.w * sc.w + sh.w, 0.f);
    if (RES) {
        float4 a = ((const float4*)A)[idx];
        h.x += a.x; h.y += a.y; h.z += a.z; h.w += a.w;
    }
    ((float4*)A)[idx] = h;
    if (W16) {
        ushort4 pk;
        pk.x = f2bf_rne(h.x); pk.y = f2bf_rne(h.y);
        pk.z = f2bf_rne(h.z); pk.w = f2bf_rne(h.w);
        *(ushort4*)(A16 + (size_t)idx * 4) = pk;
    }
}

// ---------------- output projection: out[M,10] = h[M,128] @ Wo[128,10] + bo ----------------

__global__ __launch_bounds__(256) void out_gemm(const float* __restrict__ h,
                                                const float* __restrict__ Wo,
                                                const float* __restrict__ bo,
                                                float* __restrict__ out) {
    __shared__ float Ws[HID * OUT_DIM];
    for (int i = threadIdx.x; i < HID * OUT_DIM; i += 256) Ws[i] = Wo[i];
    __syncthreads();
    int gid = blockIdx.x * blockDim.x + threadIdx.x;
    if (gid >= N_NODES * OUT_DIM) return;
    int n = gid / OUT_DIM;
    int c = gid - n * OUT_DIM;
    const float* hr = h + (size_t)n * HID;
    float s = 0.f;
    #pragma unroll 4
    for (int k = 0; k < HID; ++k) s += hr[k] * Ws[k * OUT_DIM + c];
    out[gid] = s + bo[c];
}

// ---------------- launch ----------------

extern "C" void kernel_launch(void* const* d_in, const int* in_sizes, int n_in,
                              void* d_out, int out_size, void* d_ws, size_t ws_size,
                              hipStream_t stream) {
    const float* x     = (const float*)d_in[0];
    const int*   ei    = (const int*)d_in[1];
    const int*   src   = ei;
    const int*   dst   = ei + N_EDGES;
    const float* W_in  = (const float*)d_in[2];
    const float* b_in  = (const float*)d_in[3];
    const float* Wc    = (const float*)d_in[4];
    const float* bc    = (const float*)d_in[5];
    const float* gamma = (const float*)d_in[6];
    const float* beta  = (const float*)d_in[7];
    const float* W_out = (const float*)d_in[8];
    const float* b_out = (const float*)d_in[9];
    float* out = (float*)d_out;

    char* p = (char*)d_ws;
    auto alloc = [&](size_t bytes) -> char* {
        char* q = p;
        p += (bytes + 255) & ~(size_t)255;
        return q;
    };
    float*  A         = (float*)alloc(sizeof(float) * N_NODES * HID);        // residual h (fp32)
    unsigned short* A16 = (unsigned short*)alloc(sizeof(unsigned short) * N_NODES * HID); // h bf16 (gemm input)
    uint2*  B16       = (uint2*)alloc(sizeof(unsigned short) * N_NODES * HID);            // messages bf16
    float*  C         = (float*)alloc(sizeof(float) * N_NODES * HID);        // aggregated
    float*  dinv      = (float*)alloc(sizeof(float) * N_NODES);
    int*    deg_cnt   = (int*)alloc(sizeof(int) * (N_NODES + 1));            // last int = cursor
    int*    cursor    = deg_cnt + N_NODES;
    int*    row_start = (int*)alloc(sizeof(int) * N_NODES);
    int*    fill_ptr  = (int*)alloc(sizeof(int) * N_NODES);
    int*    col_src   = (int*)alloc(sizeof(int) * N_EDGES);
    unsigned short* PWin = (unsigned short*)alloc(sizeof(unsigned short) * 4096 * 8);
    unsigned short* PWc  = (unsigned short*)alloc(sizeof(unsigned short) * 3 * 2048 * 8);
    float*  colsumAll = (float*)alloc(sizeof(float) * 3 * 256);              // per layer: [0:128) sum, [128:256) sumsq
    float*  scale     = (float*)alloc(sizeof(float) * 128);
    float*  shift     = (float*)alloc(sizeof(float) * 128);

    // CSR build
    hipMemsetAsync(deg_cnt, 0, sizeof(int) * (N_NODES + 1), stream);
    hipMemsetAsync(colsumAll, 0, sizeof(float) * 3 * 256, stream);
    count_kernel<<<(N_EDGES + 255) / 256, 256, 0, stream>>>(dst, deg_cnt);
    assign_kernel<<<(N_NODES + 255) / 256, 256, 0, stream>>>(deg_cnt, row_start, fill_ptr, dinv, cursor);
    fill_kernel<<<(N_EDGES + 255) / 256, 256, 0, stream>>>(src, dst, fill_ptr, col_src);

    // pack weights into MFMA B-fragment layout (bf16)
    pack_w_kernel<<<(4096 + 255) / 256, 256, 0, stream>>>(W_in, PWin, IN_DIM, 4096, 4096);
    pack_w_kernel<<<(3 * 2048 + 255) / 256, 256, 0, stream>>>(Wc, PWc, HID, 2048, 3 * 2048);

    // input projection + relu -> h0 (bf16 only; h0 is only ever consumed rounded)
    gemm_mfma<IN_DIM, 0, 1, 1><<<(N_NODES + 63) / 64, 256, 0, stream>>>(x, PWin, b_in, nullptr, A16, N_NODES);

    for (int l = 0; l < 3; ++l) {
        // B = (h @ Wc) * dinv[row], bf16
        gemm_mfma<HID, 1, 0, 1><<<(N_NODES + 63) / 64, 256, 0, stream>>>(A16, PWc + (size_t)l * 2048 * 8,
                                                                         nullptr, dinv, B16, N_NODES);
        float* colsum = colsumAll + l * 256;
        agg_stats_kernel<<<3125, dim3(64, 4), 0, stream>>>(B16, dinv, row_start, deg_cnt, col_src,
                                                           bc + l * HID, C, colsum, colsum + 128);
        finalize_bn<<<1, 128, 0, stream>>>(colsum, colsum + 128, gamma + l * HID, beta + l * HID, scale, shift);
        const int nblk = N_NODES * HID / 4 / 256;
        if (l == 0)      apply_bn<0, 1><<<nblk, 256, 0, stream>>>(C, scale, shift, A, A16);
        else if (l == 1) apply_bn<1, 1><<<nblk, 256, 0, stream>>>(C, scale, shift, A, A16);
        else             apply_bn<1, 0><<<nblk, 256, 0, stream>>>(C, scale, shift, A, A16);
    }

    out_gemm<<<(N_NODES * OUT_DIM + 255) / 256, 256, 0, stream>>>(A, W_out, b_out, out);
}

// Round 7
// 589.016 us; speedup vs baseline: 1.0093x; 1.0093x over previous
//
#include <hip/hip_runtime.h>

#define N_NODES 50000
#define N_EDGES 600000
#define IN_DIM 256
#define HID 128
#define OUT_DIM 10
#define BN_EPS 1e-5f

typedef unsigned int uint32;
typedef __attribute__((ext_vector_type(8))) short short8;   // 8 bf16 = 4 VGPRs
typedef __attribute__((ext_vector_type(4))) float float4v;  // MFMA acc

__device__ __forceinline__ unsigned short f2bf_rne(float f) {
    uint32 u = __float_as_uint(f);
    u += 0x7FFF + ((u >> 16) & 1);          // round-to-nearest-even
    return (unsigned short)(u >> 16);
}
__device__ __forceinline__ float bf_lo(uint32 v) { return __uint_as_float(v << 16); }
__device__ __forceinline__ float bf_hi(uint32 v) { return __uint_as_float(v & 0xFFFF0000u); }

// ---------------- edge preprocessing: CSR by dst (no prefix scan needed) ----------------

__global__ void count_kernel(const int* __restrict__ dst, int* __restrict__ cnt) {
    int e = blockIdx.x * blockDim.x + threadIdx.x;
    if (e < N_EDGES) atomicAdd(&cnt[dst[e]], 1);
}

// Wave-64 inclusive scan of counts, one atomicAdd on a global cursor per wave.
__global__ __launch_bounds__(256) void assign_kernel(const int* __restrict__ cnt,
                                                     int* __restrict__ row_start,
                                                     int* __restrict__ fill_ptr,
                                                     float* __restrict__ dinv,
                                                     int* __restrict__ cursor) {
    int i = blockIdx.x * blockDim.x + threadIdx.x;
    int c = (i < N_NODES) ? cnt[i] : 0;
    int lane = threadIdx.x & 63;
    int v = c;
    #pragma unroll
    for (int off = 1; off < 64; off <<= 1) {
        int t = __shfl_up(v, off, 64);
        if (lane >= off) v += t;
    }
    int waveTotal = __shfl(v, 63, 64);
    int base = 0;
    if (lane == 63) base = atomicAdd(cursor, waveTotal);
    base = __shfl(base, 63, 64);
    if (i < N_NODES) {
        int start = base + v - c;
        row_start[i] = start;
        fill_ptr[i] = start;
        dinv[i] = rsqrtf((float)c + 1.0f);   // +1 self-loop
    }
}

__global__ void fill_kernel(const int* __restrict__ src, const int* __restrict__ dst,
                            int* __restrict__ fill_ptr, int* __restrict__ col_src) {
    int e = blockIdx.x * blockDim.x + threadIdx.x;
    if (e < N_EDGES) {
        int d = dst[e];
        int p = atomicAdd(&fill_ptr[d], 1);
        col_src[p] = src[e];
    }
}

// ---------------- weight pre-pack into MFMA B-fragment layout ----------------
// For each layer: P[((kt*8+nt)*64+lane)*8+j] = bf16( W[kt*32+(lane>>4)*8+j][nt*16+(lane&15)] )

__global__ void pack_w_kernel(const float* __restrict__ W, unsigned short* __restrict__ P,
                              int K, int per, int total) {
    int idx = blockIdx.x * blockDim.x + threadIdx.x;
    if (idx >= total) return;
    int layer = idx / per;
    int r = idx - layer * per;
    int lane = r & 63;
    int nt = (r >> 6) & 7;
    int kt = r >> 9;
    int n = nt * 16 + (lane & 15);
    int kbase = kt * 32 + (lane >> 4) * 8;
    const float* Wl = W + (size_t)layer * K * HID;
    unsigned short* dstp = P + (size_t)idx * 8;
    #pragma unroll
    for (int j = 0; j < 8; ++j) dstp[j] = f2bf_rne(Wl[(size_t)(kbase + j) * HID + n]);
}

// ---------------- MFMA bf16 GEMM: out[M,128] = (A[M,K]@W) * rowscale (+bias)(+relu) ----------------
// block 256 = 4 waves; tile 64 rows x 128 cols. A staged in LDS, stride 40 shorts (2-way bank alias, free).
// INBF16: A is bf16 row-major [M][K]; else fp32 (converted in staging).
// MFMA mappings (m89-verified): A[m=lane&15][k=quad*8+j]; D: col=lane&15, row=quad*4+reg.

template <int K, int INBF16, int RELU, int OUTBF16>
__global__ __launch_bounds__(256) void gemm_mfma(const void* __restrict__ A_v,
                                                 const unsigned short* __restrict__ PB,
                                                 const float* __restrict__ bias,
                                                 const float* __restrict__ rowscale,
                                                 void* __restrict__ out_v, int M) {
    __shared__ unsigned short As[64 * 40];
    int tid = threadIdx.x;
    int w = tid >> 6, lane = tid & 63;
    int mrow = lane & 15, quad = lane >> 4;
    int m0 = blockIdx.x * 64;

    float4v acc[8];
    #pragma unroll
    for (int nt = 0; nt < 8; ++nt)
        #pragma unroll
        for (int i = 0; i < 4; ++i) acc[nt][i] = 0.f;

    int r = tid >> 2;        // 0..63: staging row
    int cq = tid & 3;        // col quarter (8 elements)

    for (int kt = 0; kt < K / 32; ++kt) {
        short8 pk;
        if (m0 + r < M) {
            if (INBF16) {
                pk = *(const short8*)((const unsigned short*)A_v + (size_t)(m0 + r) * K + kt * 32 + cq * 8);
            } else {
                const float* srcp = (const float*)A_v + (size_t)(m0 + r) * K + kt * 32 + cq * 8;
                float4 a0 = *(const float4*)(srcp);
                float4 a1 = *(const float4*)(srcp + 4);
                pk[0] = (short)f2bf_rne(a0.x); pk[1] = (short)f2bf_rne(a0.y);
                pk[2] = (short)f2bf_rne(a0.z); pk[3] = (short)f2bf_rne(a0.w);
                pk[4] = (short)f2bf_rne(a1.x); pk[5] = (short)f2bf_rne(a1.y);
                pk[6] = (short)f2bf_rne(a1.z); pk[7] = (short)f2bf_rne(a1.w);
            }
        } else {
            #pragma unroll
            for (int j = 0; j < 8; ++j) pk[j] = 0;
        }
        __syncthreads();                       // protect previous iteration's reads
        *(short8*)&As[r * 40 + cq * 8] = pk;
        __syncthreads();

        short8 afrag = *(const short8*)&As[(w * 16 + mrow) * 40 + quad * 8];

        const unsigned short* pb = PB + ((size_t)(kt * 8) * 64 + lane) * 8;
        #pragma unroll
        for (int nt = 0; nt < 8; ++nt) {
            short8 bfrag = *(const short8*)(pb + (size_t)nt * 64 * 8);
            acc[nt] = __builtin_amdgcn_mfma_f32_16x16x32_bf16(afrag, bfrag, acc[nt], 0, 0, 0);
        }
    }

    // epilogue: row = m0 + w*16 + quad*4 + reg, col = nt*16 + mrow
    int rowbase = m0 + w * 16 + quad * 4;
    float rs[4];
    #pragma unroll
    for (int reg = 0; reg < 4; ++reg) {
        int row = rowbase + reg;
        rs[reg] = (rowscale && row < M) ? rowscale[row] : 1.0f;
    }
    #pragma unroll
    for (int nt = 0; nt < 8; ++nt) {
        int col = nt * 16 + mrow;
        float bv = bias ? bias[col] : 0.f;
        #pragma unroll
        for (int reg = 0; reg < 4; ++reg) {
            int row = rowbase + reg;
            if (row < M) {
                float o = acc[nt][reg] * rs[reg] + bv;
                if (RELU) o = fmaxf(o, 0.f);
                if (OUTBF16)
                    ((unsigned short*)out_v)[(size_t)row * HID + col] = f2bf_rne(o);
                else
                    ((float*)out_v)[(size_t)row * HID + col] = o;
            }
        }
    }
}

// ---------------- fused CSR pull aggregation + BN column stats ----------------
// Round-4 proven gather structure: one FULL wave per node row, lane f2 -> features 2*f2, 2*f2+1
// via one uint gather; edge loop unrolled x4 => 4 independent row-gathers in flight.
// Stats fusion: each wave does 4 chunk-strided nodes, keeps col sums/sumsq in regs,
// then per-block LDS reduction + 128 atomicAdds (3125 blocks -> 400K atomics total).

__global__ __launch_bounds__(256) void agg_stats_kernel(const uint32* __restrict__ Bs32,  // [N][64]
                                                        const float* __restrict__ dinv,
                                                        const int* __restrict__ row_start,
                                                        const int* __restrict__ cnt,
                                                        const int* __restrict__ col_src,
                                                        const float* __restrict__ bc,
                                                        float* __restrict__ C,
                                                        float* __restrict__ colsum,
                                                        float* __restrict__ colsumsq) {
    __shared__ float shs[4][128];
    __shared__ float shq[4][128];
    int f2 = threadIdx.x;              // 0..63
    int ty = threadIdx.y;              // 0..3

    float2 bcv = *(const float2*)(bc + f2 * 2);
    float ss0 = 0.f, ss1 = 0.f, sq0 = 0.f, sq1 = 0.f;

    #pragma unroll
    for (int chunk = 0; chunk < 4; ++chunk) {
        int n = blockIdx.x * 4 + ty + chunk * 12500;   // covers 0..49999 exactly

        uint32 vs = Bs32[(size_t)n * 64 + f2];          // self term
        float acc0 = bf_lo(vs);
        float acc1 = bf_hi(vs);

        int beg = row_start[n];
        int end = beg + cnt[n];
        int e = beg;
        for (; e + 4 <= end; e += 4) {                  // 4 independent gathers in flight
            int s0 = col_src[e + 0];
            int s1 = col_src[e + 1];
            int s2 = col_src[e + 2];
            int s3 = col_src[e + 3];
            uint32 v0 = Bs32[(size_t)s0 * 64 + f2];
            uint32 v1 = Bs32[(size_t)s1 * 64 + f2];
            uint32 v2 = Bs32[(size_t)s2 * 64 + f2];
            uint32 v3 = Bs32[(size_t)s3 * 64 + f2];
            acc0 += bf_lo(v0); acc1 += bf_hi(v0);
            acc0 += bf_lo(v1); acc1 += bf_hi(v1);
            acc0 += bf_lo(v2); acc1 += bf_hi(v2);
            acc0 += bf_lo(v3); acc1 += bf_hi(v3);
        }
        for (; e < end; ++e) {
            int s = col_src[e];
            uint32 v = Bs32[(size_t)s * 64 + f2];
            acc0 += bf_lo(v); acc1 += bf_hi(v);
        }

        float di = dinv[n];
        float o0 = acc0 * di + bcv.x;
        float o1 = acc1 * di + bcv.y;
        *(float2*)(C + (size_t)n * HID + f2 * 2) = make_float2(o0, o1);
        ss0 += o0; ss1 += o1;
        sq0 += o0 * o0; sq1 += o1 * o1;
    }

    shs[ty][f2 * 2] = ss0; shs[ty][f2 * 2 + 1] = ss1;
    shq[ty][f2 * 2] = sq0; shq[ty][f2 * 2 + 1] = sq1;
    __syncthreads();
    int t = ty * 64 + f2;              // 0..255
    if (t < 128) {
        float s = shs[0][t] + shs[1][t] + shs[2][t] + shs[3][t];
        float q = shq[0][t] + shq[1][t] + shq[2][t] + shq[3][t];
        atomicAdd(&colsum[t], s);
        atomicAdd(&colsumsq[t], q);
    }
}

// ---------------- BN finalize / apply ----------------

__global__ void finalize_bn(const float* __restrict__ colsum, const float* __restrict__ colsumsq,
                            const float* __restrict__ gamma, const float* __restrict__ beta,
                            float* __restrict__ scale, float* __restrict__ shift) {
    int f = threadIdx.x;
    float mu = colsum[f] * (1.0f / N_NODES);
    float var = colsumsq[f] * (1.0f / N_NODES) - mu * mu;
    float rstd = rsqrtf(var + BN_EPS);
    float sc = rstd * gamma[f];
    scale[f] = sc;
    shift[f] = beta[f] - mu * sc;
}

// h = relu(C*scale+shift) (+A residual); writes A fp32, optionally A16 bf16 (next gemm input)
template <int RES, int W16>
__global__ __launch_bounds__(256) void apply_bn(const float* __restrict__ C,
                                                const float* __restrict__ scale,
                                                const float* __restrict__ shift,
                                                float* __restrict__ A,
                                                unsigned short* __restrict__ A16) {
    int idx = blockIdx.x * blockDim.x + threadIdx.x;   // float4 index
    const int total = N_NODES * HID / 4;
    if (idx >= total) return;
    int fq = idx & 31;                                  // 32 float4 per row
    float4 c = ((const float4*)C)[idx];
    float4 sc = ((const float4*)scale)[fq];
    float4 sh = ((const float4*)shift)[fq];
    float4 h;
    h.x = fmaxf(c.x * sc.x + sh.x, 0.f);
    h.y = fmaxf(c.y * sc.y + sh.y, 0.f);
    h.z = fmaxf(c.z * sc.z + sh.z, 0.f);
    h.w = fmaxf(c.w * sc.w + sh.w, 0.f);
    if (RES) {
        float4 a = ((const float4*)A)[idx];
        h.x += a.x; h.y += a.y; h.z += a.z; h.w += a.w;
    }
    ((float4*)A)[idx] = h;
    if (W16) {
        ushort4 pk;
        pk.x = f2bf_rne(h.x); pk.y = f2bf_rne(h.y);
        pk.z = f2bf_rne(h.z); pk.w = f2bf_rne(h.w);
        *(ushort4*)(A16 + (size_t)idx * 4) = pk;
    }
}

// ---------------- output projection: out[M,10] = h[M,128] @ Wo[128,10] + bo ----------------

__global__ __launch_bounds__(256) void out_gemm(const float* __restrict__ h,
                                                const float* __restrict__ Wo,
                                                const float* __restrict__ bo,
                                                float* __restrict__ out) {
    __shared__ float Ws[HID * OUT_DIM];
    for (int i = threadIdx.x; i < HID * OUT_DIM; i += 256) Ws[i] = Wo[i];
    __syncthreads();
    int gid = blockIdx.x * blockDim.x + threadIdx.x;
    if (gid >= N_NODES * OUT_DIM) return;
    int n = gid / OUT_DIM;
    int c = gid - n * OUT_DIM;
    const float* hr = h + (size_t)n * HID;
    float s = 0.f;
    #pragma unroll 4
    for (int k = 0; k < HID; ++k) s += hr[k] * Ws[k * OUT_DIM + c];
    out[gid] = s + bo[c];
}

// ---------------- launch ----------------

extern "C" void kernel_launch(void* const* d_in, const int* in_sizes, int n_in,
                              void* d_out, int out_size, void* d_ws, size_t ws_size,
                              hipStream_t stream) {
    const float* x     = (const float*)d_in[0];
    const int*   ei    = (const int*)d_in[1];
    const int*   src   = ei;
    const int*   dst   = ei + N_EDGES;
    const float* W_in  = (const float*)d_in[2];
    const float* b_in  = (const float*)d_in[3];
    const float* Wc    = (const float*)d_in[4];
    const float* bc    = (const float*)d_in[5];
    const float* gamma = (const float*)d_in[6];
    const float* beta  = (const float*)d_in[7];
    const float* W_out = (const float*)d_in[8];
    const float* b_out = (const float*)d_in[9];
    float* out = (float*)d_out;

    char* p = (char*)d_ws;
    auto alloc = [&](size_t bytes) -> char* {
        char* q = p;
        p += (bytes + 255) & ~(size_t)255;
        return q;
    };
    float*  A         = (float*)alloc(sizeof(float) * N_NODES * HID);        // residual h (fp32)
    unsigned short* A16 = (unsigned short*)alloc(sizeof(unsigned short) * N_NODES * HID); // h bf16 (gemm input)
    uint32* B16       = (uint32*)alloc(sizeof(unsigned short) * N_NODES * HID);           // messages bf16
    float*  C         = (float*)alloc(sizeof(float) * N_NODES * HID);        // aggregated
    float*  dinv      = (float*)alloc(sizeof(float) * N_NODES);
    int*    deg_cnt   = (int*)alloc(sizeof(int) * (N_NODES + 1));            // last int = cursor
    int*    cursor    = deg_cnt + N_NODES;
    int*    row_start = (int*)alloc(sizeof(int) * N_NODES);
    int*    fill_ptr  = (int*)alloc(sizeof(int) * N_NODES);
    int*    col_src   = (int*)alloc(sizeof(int) * N_EDGES);
    unsigned short* PWin = (unsigned short*)alloc(sizeof(unsigned short) * 4096 * 8);
    unsigned short* PWc  = (unsigned short*)alloc(sizeof(unsigned short) * 3 * 2048 * 8);
    float*  colsumAll = (float*)alloc(sizeof(float) * 3 * 256);              // per layer: [0:128) sum, [128:256) sumsq
    float*  scale     = (float*)alloc(sizeof(float) * 128);
    float*  shift     = (float*)alloc(sizeof(float) * 128);

    // CSR build
    hipMemsetAsync(deg_cnt, 0, sizeof(int) * (N_NODES + 1), stream);
    hipMemsetAsync(colsumAll, 0, sizeof(float) * 3 * 256, stream);
    count_kernel<<<(N_EDGES + 255) / 256, 256, 0, stream>>>(dst, deg_cnt);
    assign_kernel<<<(N_NODES + 255) / 256, 256, 0, stream>>>(deg_cnt, row_start, fill_ptr, dinv, cursor);
    fill_kernel<<<(N_EDGES + 255) / 256, 256, 0, stream>>>(src, dst, fill_ptr, col_src);

    // pack weights into MFMA B-fragment layout (bf16)
    pack_w_kernel<<<(4096 + 255) / 256, 256, 0, stream>>>(W_in, PWin, IN_DIM, 4096, 4096);
    pack_w_kernel<<<(3 * 2048 + 255) / 256, 256, 0, stream>>>(Wc, PWc, HID, 2048, 3 * 2048);

    // input projection + relu -> h0 (bf16; h0 is only ever consumed rounded)
    gemm_mfma<IN_DIM, 0, 1, 1><<<(N_NODES + 63) / 64, 256, 0, stream>>>(x, PWin, b_in, nullptr, A16, N_NODES);

    for (int l = 0; l < 3; ++l) {
        // B = (h @ Wc) * dinv[row], bf16
        gemm_mfma<HID, 1, 0, 1><<<(N_NODES + 63) / 64, 256, 0, stream>>>(A16, PWc + (size_t)l * 2048 * 8,
                                                                         nullptr, dinv, B16, N_NODES);
        float* colsum = colsumAll + l * 256;
        agg_stats_kernel<<<3125, dim3(64, 4), 0, stream>>>(B16, dinv, row_start, deg_cnt, col_src,
                                                           bc + l * HID, C, colsum, colsum + 128);
        finalize_bn<<<1, 128, 0, stream>>>(colsum, colsum + 128, gamma + l * HID, beta + l * HID, scale, shift);
        const int nblk = N_NODES * HID / 4 / 256;
        if (l == 0)      apply_bn<0, 1><<<nblk, 256, 0, stream>>>(C, scale, shift, A, A16);
        else if (l == 1) apply_bn<1, 1><<<nblk, 256, 0, stream>>>(C, scale, shift, A, A16);
        else             apply_bn<1, 0><<<nblk, 256, 0, stream>>>(C, scale, shift, A, A16);
    }

    out_gemm<<<(N_NODES * OUT_DIM + 255) / 256, 256, 0, stream>>>(A, W_out, b_out, out);
}

// Round 8
// 411.033 us; speedup vs baseline: 1.4463x; 1.4330x over previous
//
#include <hip/hip_runtime.h>

#define N_NODES 50000
#define N_EDGES 600000
#define IN_DIM 256
#define HID 128
#define OUT_DIM 10
#define BN_EPS 1e-5f

typedef unsigned int uint32;
typedef __attribute__((ext_vector_type(8))) short short8;   // 8 bf16 = 4 VGPRs
typedef __attribute__((ext_vector_type(4))) float float4v;  // MFMA acc

__device__ __forceinline__ unsigned short f2bf_rne(float f) {
    uint32 u = __float_as_uint(f);
    u += 0x7FFF + ((u >> 16) & 1);          // round-to-nearest-even
    return (unsigned short)(u >> 16);
}
__device__ __forceinline__ float bf_lo(uint32 v) { return __uint_as_float(v << 16); }
__device__ __forceinline__ float bf_hi(uint32 v) { return __uint_as_float(v & 0xFFFF0000u); }

// ---------------- edge preprocessing: CSR by dst (no prefix scan needed) ----------------

__global__ void count_kernel(const int* __restrict__ dst, int* __restrict__ cnt) {
    int e = blockIdx.x * blockDim.x + threadIdx.x;
    if (e < N_EDGES) atomicAdd(&cnt[dst[e]], 1);
}

// Wave-64 inclusive scan of counts, one atomicAdd on a global cursor per wave.
__global__ __launch_bounds__(256) void assign_kernel(const int* __restrict__ cnt,
                                                     int* __restrict__ row_start,
                                                     int* __restrict__ fill_ptr,
                                                     float* __restrict__ dinv,
                                                     int* __restrict__ cursor) {
    int i = blockIdx.x * blockDim.x + threadIdx.x;
    int c = (i < N_NODES) ? cnt[i] : 0;
    int lane = threadIdx.x & 63;
    int v = c;
    #pragma unroll
    for (int off = 1; off < 64; off <<= 1) {
        int t = __shfl_up(v, off, 64);
        if (lane >= off) v += t;
    }
    int waveTotal = __shfl(v, 63, 64);
    int base = 0;
    if (lane == 63) base = atomicAdd(cursor, waveTotal);
    base = __shfl(base, 63, 64);
    if (i < N_NODES) {
        int start = base + v - c;
        row_start[i] = start;
        fill_ptr[i] = start;
        dinv[i] = rsqrtf((float)c + 1.0f);   // +1 self-loop
    }
}

__global__ void fill_kernel(const int* __restrict__ src, const int* __restrict__ dst,
                            int* __restrict__ fill_ptr, int* __restrict__ col_src) {
    int e = blockIdx.x * blockDim.x + threadIdx.x;
    if (e < N_EDGES) {
        int d = dst[e];
        int p = atomicAdd(&fill_ptr[d], 1);
        col_src[p] = src[e];
    }
}

// ---------------- weight pre-pack into MFMA B-fragment layout ----------------
// For each layer: P[((kt*8+nt)*64+lane)*8+j] = bf16( W[kt*32+(lane>>4)*8+j][nt*16+(lane&15)] )

__global__ void pack_w_kernel(const float* __restrict__ W, unsigned short* __restrict__ P,
                              int K, int per, int total) {
    int idx = blockIdx.x * blockDim.x + threadIdx.x;
    if (idx >= total) return;
    int layer = idx / per;
    int r = idx - layer * per;
    int lane = r & 63;
    int nt = (r >> 6) & 7;
    int kt = r >> 9;
    int n = nt * 16 + (lane & 15);
    int kbase = kt * 32 + (lane >> 4) * 8;
    const float* Wl = W + (size_t)layer * K * HID;
    unsigned short* dstp = P + (size_t)idx * 8;
    #pragma unroll
    for (int j = 0; j < 8; ++j) dstp[j] = f2bf_rne(Wl[(size_t)(kbase + j) * HID + n]);
}

// ---------------- MFMA bf16 GEMM: out[M,128] = (A[M,K]@W) * rowscale (+bias)(+relu) ----------------
// block 256 = 4 waves; tile 64 rows x 128 cols. A staged in LDS, stride 40 shorts (2-way bank alias, free).
// INBF16: A is bf16 row-major [M][K]; else fp32 (converted in staging).
// MFMA mappings (m89-verified): A[m=lane&15][k=quad*8+j]; D: col=lane&15, row=quad*4+reg.

template <int K, int INBF16, int RELU, int OUTBF16>
__global__ __launch_bounds__(256) void gemm_mfma(const void* __restrict__ A_v,
                                                 const unsigned short* __restrict__ PB,
                                                 const float* __restrict__ bias,
                                                 const float* __restrict__ rowscale,
                                                 void* __restrict__ out_v, int M) {
    __shared__ unsigned short As[64 * 40];
    int tid = threadIdx.x;
    int w = tid >> 6, lane = tid & 63;
    int mrow = lane & 15, quad = lane >> 4;
    int m0 = blockIdx.x * 64;

    float4v acc[8];
    #pragma unroll
    for (int nt = 0; nt < 8; ++nt)
        #pragma unroll
        for (int i = 0; i < 4; ++i) acc[nt][i] = 0.f;

    int r = tid >> 2;        // 0..63: staging row
    int cq = tid & 3;        // col quarter (8 elements)

    for (int kt = 0; kt < K / 32; ++kt) {
        short8 pk;
        if (m0 + r < M) {
            if (INBF16) {
                pk = *(const short8*)((const unsigned short*)A_v + (size_t)(m0 + r) * K + kt * 32 + cq * 8);
            } else {
                const float* srcp = (const float*)A_v + (size_t)(m0 + r) * K + kt * 32 + cq * 8;
                float4 a0 = *(const float4*)(srcp);
                float4 a1 = *(const float4*)(srcp + 4);
                pk[0] = (short)f2bf_rne(a0.x); pk[1] = (short)f2bf_rne(a0.y);
                pk[2] = (short)f2bf_rne(a0.z); pk[3] = (short)f2bf_rne(a0.w);
                pk[4] = (short)f2bf_rne(a1.x); pk[5] = (short)f2bf_rne(a1.y);
                pk[6] = (short)f2bf_rne(a1.z); pk[7] = (short)f2bf_rne(a1.w);
            }
        } else {
            #pragma unroll
            for (int j = 0; j < 8; ++j) pk[j] = 0;
        }
        __syncthreads();                       // protect previous iteration's reads
        *(short8*)&As[r * 40 + cq * 8] = pk;
        __syncthreads();

        short8 afrag = *(const short8*)&As[(w * 16 + mrow) * 40 + quad * 8];

        const unsigned short* pb = PB + ((size_t)(kt * 8) * 64 + lane) * 8;
        #pragma unroll
        for (int nt = 0; nt < 8; ++nt) {
            short8 bfrag = *(const short8*)(pb + (size_t)nt * 64 * 8);
            acc[nt] = __builtin_amdgcn_mfma_f32_16x16x32_bf16(afrag, bfrag, acc[nt], 0, 0, 0);
        }
    }

    // epilogue: row = m0 + w*16 + quad*4 + reg, col = nt*16 + mrow
    int rowbase = m0 + w * 16 + quad * 4;
    float rs[4];
    #pragma unroll
    for (int reg = 0; reg < 4; ++reg) {
        int row = rowbase + reg;
        rs[reg] = (rowscale && row < M) ? rowscale[row] : 1.0f;
    }
    #pragma unroll
    for (int nt = 0; nt < 8; ++nt) {
        int col = nt * 16 + mrow;
        float bv = bias ? bias[col] : 0.f;
        #pragma unroll
        for (int reg = 0; reg < 4; ++reg) {
            int row = rowbase + reg;
            if (row < M) {
                float o = acc[nt][reg] * rs[reg] + bv;
                if (RELU) o = fmaxf(o, 0.f);
                if (OUTBF16)
                    ((unsigned short*)out_v)[(size_t)row * HID + col] = f2bf_rne(o);
                else
                    ((float*)out_v)[(size_t)row * HID + col] = o;
            }
        }
    }
}

// ---------------- fused CSR pull aggregation + BN column stats ----------------
// ONE NODE PER WAVE (round-5 winning shape): grid 12500 x (64,4), lane f2 -> features
// 2*f2,2*f2+1 via one uint gather, edge loop unrolled x4 (4 gathers in flight).
// Stats: per-block LDS reduce of the 4 nodes' C rows, then atomicAdd into one of 32
// hashed accumulator copies (colsum_multi[blockIdx&31][256]) to bound serialization.

__global__ __launch_bounds__(256) void agg_stats_kernel(const uint32* __restrict__ Bs32,  // [N][64]
                                                        const float* __restrict__ dinv,
                                                        const int* __restrict__ row_start,
                                                        const int* __restrict__ cnt,
                                                        const int* __restrict__ col_src,
                                                        const float* __restrict__ bc,
                                                        float* __restrict__ C,
                                                        float* __restrict__ colsum_multi) { // [32][256]
    __shared__ float shs[4][128];
    __shared__ float shq[4][128];
    int f2 = threadIdx.x;              // 0..63
    int ty = threadIdx.y;              // 0..3
    int n = blockIdx.x * 4 + ty;       // N_NODES % 4 == 0

    uint32 vs = Bs32[(size_t)n * 64 + f2];          // self term
    float acc0 = bf_lo(vs);
    float acc1 = bf_hi(vs);

    int beg = row_start[n];
    int end = beg + cnt[n];
    int e = beg;
    for (; e + 4 <= end; e += 4) {                  // 4 independent gathers in flight
        int s0 = col_src[e + 0];
        int s1 = col_src[e + 1];
        int s2 = col_src[e + 2];
        int s3 = col_src[e + 3];
        uint32 v0 = Bs32[(size_t)s0 * 64 + f2];
        uint32 v1 = Bs32[(size_t)s1 * 64 + f2];
        uint32 v2 = Bs32[(size_t)s2 * 64 + f2];
        uint32 v3 = Bs32[(size_t)s3 * 64 + f2];
        acc0 += bf_lo(v0); acc1 += bf_hi(v0);
        acc0 += bf_lo(v1); acc1 += bf_hi(v1);
        acc0 += bf_lo(v2); acc1 += bf_hi(v2);
        acc0 += bf_lo(v3); acc1 += bf_hi(v3);
    }
    for (; e < end; ++e) {
        int s = col_src[e];
        uint32 v = Bs32[(size_t)s * 64 + f2];
        acc0 += bf_lo(v); acc1 += bf_hi(v);
    }

    float di = dinv[n];
    float2 bcv = *(const float2*)(bc + f2 * 2);
    float o0 = acc0 * di + bcv.x;
    float o1 = acc1 * di + bcv.y;
    *(float2*)(C + (size_t)n * HID + f2 * 2) = make_float2(o0, o1);

    shs[ty][f2 * 2] = o0; shs[ty][f2 * 2 + 1] = o1;
    shq[ty][f2 * 2] = o0 * o0; shq[ty][f2 * 2 + 1] = o1 * o1;
    __syncthreads();
    int t = ty * 64 + f2;              // 0..255
    if (t < 128) {
        float s = shs[0][t] + shs[1][t] + shs[2][t] + shs[3][t];
        float q = shq[0][t] + shq[1][t] + shq[2][t] + shq[3][t];
        float* base = colsum_multi + (size_t)(blockIdx.x & 31) * 256;
        atomicAdd(&base[t], s);
        atomicAdd(&base[t + 128], q);
    }
}

// ---------------- BN finalize / apply ----------------

__global__ void finalize_bn(const float* __restrict__ colsum_multi,   // [32][256]
                            const float* __restrict__ gamma, const float* __restrict__ beta,
                            float* __restrict__ scale, float* __restrict__ shift) {
    int f = threadIdx.x;
    float s = 0.f, q = 0.f;
    #pragma unroll
    for (int c = 0; c < 32; ++c) {
        s += colsum_multi[c * 256 + f];
        q += colsum_multi[c * 256 + f + 128];
    }
    float mu = s * (1.0f / N_NODES);
    float var = q * (1.0f / N_NODES) - mu * mu;
    float rstd = rsqrtf(var + BN_EPS);
    float sc = rstd * gamma[f];
    scale[f] = sc;
    shift[f] = beta[f] - mu * sc;
}

// h = relu(C*scale+shift) (+A residual); writes A fp32, optionally A16 bf16 (next gemm input)
template <int RES, int W16>
__global__ __launch_bounds__(256) void apply_bn(const float* __restrict__ C,
                                                const float* __restrict__ scale,
                                                const float* __restrict__ shift,
                                                float* __restrict__ A,
                                                unsigned short* __restrict__ A16) {
    int idx = blockIdx.x * blockDim.x + threadIdx.x;   // float4 index
    const int total = N_NODES * HID / 4;
    if (idx >= total) return;
    int fq = idx & 31;                                  // 32 float4 per row
    float4 c = ((const float4*)C)[idx];
    float4 sc = ((const float4*)scale)[fq];
    float4 sh = ((const float4*)shift)[fq];
    float4 h;
    h.x = fmaxf(c.x * sc.x + sh.x, 0.f);
    h.y = fmaxf(c.y * sc.y + sh.y, 0.f);
    h.z = fmaxf(c.z * sc.z + sh.z, 0.f);
    h.w = fmaxf(c.w * sc.w + sh.w, 0.f);
    if (RES) {
        float4 a = ((const float4*)A)[idx];
        h.x += a.x; h.y += a.y; h.z += a.z; h.w += a.w;
    }
    ((float4*)A)[idx] = h;
    if (W16) {
        ushort4 pk;
        pk.x = f2bf_rne(h.x); pk.y = f2bf_rne(h.y);
        pk.z = f2bf_rne(h.z); pk.w = f2bf_rne(h.w);
        *(ushort4*)(A16 + (size_t)idx * 4) = pk;
    }
}

// ---------------- output projection: out[M,10] = h[M,128] @ Wo[128,10] + bo ----------------

__global__ __launch_bounds__(256) void out_gemm(const float* __restrict__ h,
                                                const float* __restrict__ Wo,
                                                const float* __restrict__ bo,
                                                float* __restrict__ out) {
    __shared__ float Ws[HID * OUT_DIM];
    for (int i = threadIdx.x; i < HID * OUT_DIM; i += 256) Ws[i] = Wo[i];
    __syncthreads();
    int gid = blockIdx.x * blockDim.x + threadIdx.x;
    if (gid >= N_NODES * OUT_DIM) return;
    int n = gid / OUT_DIM;
    int c = gid - n * OUT_DIM;
    const float* hr = h + (size_t)n * HID;
    float s = 0.f;
    #pragma unroll 4
    for (int k = 0; k < HID; ++k) s += hr[k] * Ws[k * OUT_DIM + c];
    out[gid] = s + bo[c];
}

// ---------------- launch ----------------

extern "C" void kernel_launch(void* const* d_in, const int* in_sizes, int n_in,
                              void* d_out, int out_size, void* d_ws, size_t ws_size,
                              hipStream_t stream) {
    const float* x     = (const float*)d_in[0];
    const int*   ei    = (const int*)d_in[1];
    const int*   src   = ei;
    const int*   dst   = ei + N_EDGES;
    const float* W_in  = (const float*)d_in[2];
    const float* b_in  = (const float*)d_in[3];
    const float* Wc    = (const float*)d_in[4];
    const float* bc    = (const float*)d_in[5];
    const float* gamma = (const float*)d_in[6];
    const float* beta  = (const float*)d_in[7];
    const float* W_out = (const float*)d_in[8];
    const float* b_out = (const float*)d_in[9];
    float* out = (float*)d_out;

    char* p = (char*)d_ws;
    auto alloc = [&](size_t bytes) -> char* {
        char* q = p;
        p += (bytes + 255) & ~(size_t)255;
        return q;
    };
    float*  A         = (float*)alloc(sizeof(float) * N_NODES * HID);        // residual h (fp32)
    unsigned short* A16 = (unsigned short*)alloc(sizeof(unsigned short) * N_NODES * HID); // h bf16 (gemm input)
    uint32* B16       = (uint32*)alloc(sizeof(unsigned short) * N_NODES * HID);           // messages bf16
    float*  C         = (float*)alloc(sizeof(float) * N_NODES * HID);        // aggregated
    float*  dinv      = (float*)alloc(sizeof(float) * N_NODES);
    int*    deg_cnt   = (int*)alloc(sizeof(int) * (N_NODES + 1));            // last int = cursor
    int*    cursor    = deg_cnt + N_NODES;
    int*    row_start = (int*)alloc(sizeof(int) * N_NODES);
    int*    fill_ptr  = (int*)alloc(sizeof(int) * N_NODES);
    int*    col_src   = (int*)alloc(sizeof(int) * N_EDGES);
    unsigned short* PWin = (unsigned short*)alloc(sizeof(unsigned short) * 4096 * 8);
    unsigned short* PWc  = (unsigned short*)alloc(sizeof(unsigned short) * 3 * 2048 * 8);
    float*  colsumAll = (float*)alloc(sizeof(float) * 3 * 32 * 256);         // per layer: 32 hashed copies of [sum|sumsq]
    float*  scale     = (float*)alloc(sizeof(float) * 128);
    float*  shift     = (float*)alloc(sizeof(float) * 128);

    // CSR build
    hipMemsetAsync(deg_cnt, 0, sizeof(int) * (N_NODES + 1), stream);
    hipMemsetAsync(colsumAll, 0, sizeof(float) * 3 * 32 * 256, stream);
    count_kernel<<<(N_EDGES + 255) / 256, 256, 0, stream>>>(dst, deg_cnt);
    assign_kernel<<<(N_NODES + 255) / 256, 256, 0, stream>>>(deg_cnt, row_start, fill_ptr, dinv, cursor);
    fill_kernel<<<(N_EDGES + 255) / 256, 256, 0, stream>>>(src, dst, fill_ptr, col_src);

    // pack weights into MFMA B-fragment layout (bf16)
    pack_w_kernel<<<(4096 + 255) / 256, 256, 0, stream>>>(W_in, PWin, IN_DIM, 4096, 4096);
    pack_w_kernel<<<(3 * 2048 + 255) / 256, 256, 0, stream>>>(Wc, PWc, HID, 2048, 3 * 2048);

    // input projection + relu -> h0 (bf16; h0 is only ever consumed rounded)
    gemm_mfma<IN_DIM, 0, 1, 1><<<(N_NODES + 63) / 64, 256, 0, stream>>>(x, PWin, b_in, nullptr, A16, N_NODES);

    for (int l = 0; l < 3; ++l) {
        // B = (h @ Wc) * dinv[row], bf16
        gemm_mfma<HID, 1, 0, 1><<<(N_NODES + 63) / 64, 256, 0, stream>>>(A16, PWc + (size_t)l * 2048 * 8,
                                                                         nullptr, dinv, B16, N_NODES);
        float* colsum = colsumAll + (size_t)l * 32 * 256;
        agg_stats_kernel<<<N_NODES / 4, dim3(64, 4), 0, stream>>>(B16, dinv, row_start, deg_cnt, col_src,
                                                                  bc + l * HID, C, colsum);
        finalize_bn<<<1, 128, 0, stream>>>(colsum, gamma + l * HID, beta + l * HID, scale, shift);
        const int nblk = N_NODES * HID / 4 / 256;
        if (l == 0)      apply_bn<0, 1><<<nblk, 256, 0, stream>>>(C, scale, shift, A, A16);
        else if (l == 1) apply_bn<1, 1><<<nblk, 256, 0, stream>>>(C, scale, shift, A, A16);
        else             apply_bn<1, 0><<<nblk, 256, 0, stream>>>(C, scale, shift, A, A16);
    }

    out_gemm<<<(N_NODES * OUT_DIM + 255) / 256, 256, 0, stream>>>(A, W_out, b_out, out);
}

// Round 9
// 389.245 us; speedup vs baseline: 1.5272x; 1.0560x over previous
//
#include <hip/hip_runtime.h>

#define N_NODES 50000
#define N_EDGES 600000
#define IN_DIM 256
#define HID 128
#define OUT_DIM 10
#define BN_EPS 1e-5f

typedef unsigned int uint32;
typedef __attribute__((ext_vector_type(8))) short short8;   // 8 bf16 = 4 VGPRs
typedef __attribute__((ext_vector_type(4))) float float4v;  // MFMA acc

__device__ __forceinline__ unsigned short f2bf_rne(float f) {
    uint32 u = __float_as_uint(f);
    u += 0x7FFF + ((u >> 16) & 1);          // round-to-nearest-even
    return (unsigned short)(u >> 16);
}
__device__ __forceinline__ float bf_lo(uint32 v) { return __uint_as_float(v << 16); }
__device__ __forceinline__ float bf_hi(uint32 v) { return __uint_as_float(v & 0xFFFF0000u); }

// ---------------- edge preprocessing: CSR by dst (no prefix scan needed) ----------------

__global__ void count_kernel(const int* __restrict__ dst, int* __restrict__ cnt) {
    int e = blockIdx.x * blockDim.x + threadIdx.x;
    if (e < N_EDGES) atomicAdd(&cnt[dst[e]], 1);
}

// Wave-64 inclusive scan of counts, one atomicAdd on a global cursor per wave.
__global__ __launch_bounds__(256) void assign_kernel(const int* __restrict__ cnt,
                                                     int* __restrict__ row_start,
                                                     int* __restrict__ fill_ptr,
                                                     float* __restrict__ dinv,
                                                     int* __restrict__ cursor) {
    int i = blockIdx.x * blockDim.x + threadIdx.x;
    int c = (i < N_NODES) ? cnt[i] : 0;
    int lane = threadIdx.x & 63;
    int v = c;
    #pragma unroll
    for (int off = 1; off < 64; off <<= 1) {
        int t = __shfl_up(v, off, 64);
        if (lane >= off) v += t;
    }
    int waveTotal = __shfl(v, 63, 64);
    int base = 0;
    if (lane == 63) base = atomicAdd(cursor, waveTotal);
    base = __shfl(base, 63, 64);
    if (i < N_NODES) {
        int start = base + v - c;
        row_start[i] = start;
        fill_ptr[i] = start;
        dinv[i] = rsqrtf((float)c + 1.0f);   // +1 self-loop
    }
}

__global__ void fill_kernel(const int* __restrict__ src, const int* __restrict__ dst,
                            int* __restrict__ fill_ptr, int* __restrict__ col_src) {
    int e = blockIdx.x * blockDim.x + threadIdx.x;
    if (e < N_EDGES) {
        int d = dst[e];
        int p = atomicAdd(&fill_ptr[d], 1);
        col_src[p] = src[e];
    }
}

// ---------------- weight pre-pack into MFMA B-fragment layout ----------------

__global__ void pack_w_kernel(const float* __restrict__ W, unsigned short* __restrict__ P,
                              int K, int per, int total) {
    int idx = blockIdx.x * blockDim.x + threadIdx.x;
    if (idx >= total) return;
    int layer = idx / per;
    int r = idx - layer * per;
    int lane = r & 63;
    int nt = (r >> 6) & 7;
    int kt = r >> 9;
    int n = nt * 16 + (lane & 15);
    int kbase = kt * 32 + (lane >> 4) * 8;
    const float* Wl = W + (size_t)layer * K * HID;
    unsigned short* dstp = P + (size_t)idx * 8;
    #pragma unroll
    for (int j = 0; j < 8; ++j) dstp[j] = f2bf_rne(Wl[(size_t)(kbase + j) * HID + n]);
}

// ---------------- MFMA bf16 GEMM ----------------
// out[M,128] = (in[M,K]@W) * rowscale (+bias)(+relu-epilogue)
// MODE 0: in = bf16 [M][K].  MODE 1: in = fp32 [M][K].
// MODE 2: fused BN-apply: in = C fp32; staging computes h = relu(C*sc+sh) (+Aold if RES),
//         writes h to hout fp32 and feeds bf16(h) into the MFMA.
// block 256 = 4 waves; tile 64x128; LDS stride 40 shorts (2-way alias, free).
// MFMA mappings (m89-verified): A[m=lane&15][k=quad*8+j]; D: col=lane&15, row=quad*4+reg.

template <int K, int MODE, int RES, int RELU, int OUTBF16>
__global__ __launch_bounds__(256) void gemm_mfma(const void* __restrict__ A_v,
                                                 const unsigned short* __restrict__ PB,
                                                 const float* __restrict__ bias,
                                                 const float* __restrict__ rowscale,
                                                 const float* __restrict__ sc_,
                                                 const float* __restrict__ sh_,
                                                 float* __restrict__ hout,
                                                 void* __restrict__ out_v, int M) {
    __shared__ unsigned short As[64 * 40];
    int tid = threadIdx.x;
    int w = tid >> 6, lane = tid & 63;
    int mrow = lane & 15, quad = lane >> 4;
    int m0 = blockIdx.x * 64;

    float4v acc[8];
    #pragma unroll
    for (int nt = 0; nt < 8; ++nt)
        #pragma unroll
        for (int i = 0; i < 4; ++i) acc[nt][i] = 0.f;

    int r = tid >> 2;        // 0..63: staging row
    int cq = tid & 3;        // col quarter (8 elements)

    for (int kt = 0; kt < K / 32; ++kt) {
        short8 pk;
        int row = m0 + r;
        int col0 = kt * 32 + cq * 8;
        if (row < M) {
            if (MODE == 0) {
                pk = *(const short8*)((const unsigned short*)A_v + (size_t)row * K + col0);
            } else if (MODE == 1) {
                const float* srcp = (const float*)A_v + (size_t)row * K + col0;
                float4 a0 = *(const float4*)(srcp);
                float4 a1 = *(const float4*)(srcp + 4);
                pk[0] = (short)f2bf_rne(a0.x); pk[1] = (short)f2bf_rne(a0.y);
                pk[2] = (short)f2bf_rne(a0.z); pk[3] = (short)f2bf_rne(a0.w);
                pk[4] = (short)f2bf_rne(a1.x); pk[5] = (short)f2bf_rne(a1.y);
                pk[6] = (short)f2bf_rne(a1.z); pk[7] = (short)f2bf_rne(a1.w);
            } else {
                const float* srcp = (const float*)A_v + (size_t)row * K + col0;
                float4 c0 = *(const float4*)(srcp);
                float4 c1 = *(const float4*)(srcp + 4);
                float4 s0 = *(const float4*)(sc_ + col0);
                float4 s1 = *(const float4*)(sc_ + col0 + 4);
                float4 t0 = *(const float4*)(sh_ + col0);
                float4 t1 = *(const float4*)(sh_ + col0 + 4);
                float h0 = fmaxf(c0.x * s0.x + t0.x, 0.f);
                float h1 = fmaxf(c0.y * s0.y + t0.y, 0.f);
                float h2 = fmaxf(c0.z * s0.z + t0.z, 0.f);
                float h3 = fmaxf(c0.w * s0.w + t0.w, 0.f);
                float h4 = fmaxf(c1.x * s1.x + t1.x, 0.f);
                float h5 = fmaxf(c1.y * s1.y + t1.y, 0.f);
                float h6 = fmaxf(c1.z * s1.z + t1.z, 0.f);
                float h7 = fmaxf(c1.w * s1.w + t1.w, 0.f);
                if (RES) {
                    const float* ap = hout + (size_t)row * K + col0;
                    float4 a0 = *(const float4*)(ap);
                    float4 a1 = *(const float4*)(ap + 4);
                    h0 += a0.x; h1 += a0.y; h2 += a0.z; h3 += a0.w;
                    h4 += a1.x; h5 += a1.y; h6 += a1.z; h7 += a1.w;
                }
                float* op = hout + (size_t)row * K + col0;
                *(float4*)(op) = make_float4(h0, h1, h2, h3);
                *(float4*)(op + 4) = make_float4(h4, h5, h6, h7);
                pk[0] = (short)f2bf_rne(h0); pk[1] = (short)f2bf_rne(h1);
                pk[2] = (short)f2bf_rne(h2); pk[3] = (short)f2bf_rne(h3);
                pk[4] = (short)f2bf_rne(h4); pk[5] = (short)f2bf_rne(h5);
                pk[6] = (short)f2bf_rne(h6); pk[7] = (short)f2bf_rne(h7);
            }
        } else {
            #pragma unroll
            for (int j = 0; j < 8; ++j) pk[j] = 0;
        }
        __syncthreads();                       // protect previous iteration's reads
        *(short8*)&As[r * 40 + cq * 8] = pk;
        __syncthreads();

        short8 afrag = *(const short8*)&As[(w * 16 + mrow) * 40 + quad * 8];

        const unsigned short* pb = PB + ((size_t)(kt * 8) * 64 + lane) * 8;
        #pragma unroll
        for (int nt = 0; nt < 8; ++nt) {
            short8 bfrag = *(const short8*)(pb + (size_t)nt * 64 * 8);
            acc[nt] = __builtin_amdgcn_mfma_f32_16x16x32_bf16(afrag, bfrag, acc[nt], 0, 0, 0);
        }
    }

    // epilogue: row = m0 + w*16 + quad*4 + reg, col = nt*16 + mrow
    int rowbase = m0 + w * 16 + quad * 4;
    float rs[4];
    #pragma unroll
    for (int reg = 0; reg < 4; ++reg) {
        int row = rowbase + reg;
        rs[reg] = (rowscale && row < M) ? rowscale[row] : 1.0f;
    }
    #pragma unroll
    for (int nt = 0; nt < 8; ++nt) {
        int col = nt * 16 + mrow;
        float bv = bias ? bias[col] : 0.f;
        #pragma unroll
        for (int reg = 0; reg < 4; ++reg) {
            int row = rowbase + reg;
            if (row < M) {
                float o = acc[nt][reg] * rs[reg] + bv;
                if (RELU) o = fmaxf(o, 0.f);
                if (OUTBF16)
                    ((unsigned short*)out_v)[(size_t)row * HID + col] = f2bf_rne(o);
                else
                    ((float*)out_v)[(size_t)row * HID + col] = o;
            }
        }
    }
}

// ---------------- fused CSR pull aggregation + BN column stats ----------------
// One node per wave, grid 12500 x (64,4); lane f2 -> features 2*f2,2*f2+1 (one uint gather).
// Masked index-clamped unroll-4: every gather 4-deep in flight, no serial tail.
// Stats: per-block LDS reduce, atomicAdd into 32 hashed accumulator copies.

__global__ __launch_bounds__(256) void agg_stats_kernel(const uint32* __restrict__ Bs32,  // [N][64]
                                                        const float* __restrict__ dinv,
                                                        const int* __restrict__ row_start,
                                                        const int* __restrict__ cnt,
                                                        const int* __restrict__ col_src,
                                                        const float* __restrict__ bc,
                                                        float* __restrict__ C,
                                                        float* __restrict__ colsum_multi) { // [32][256]
    __shared__ float shs[4][128];
    __shared__ float shq[4][128];
    int f2 = threadIdx.x;              // 0..63
    int ty = threadIdx.y;              // 0..3
    int n = blockIdx.x * 4 + ty;       // N_NODES % 4 == 0

    uint32 vs = Bs32[(size_t)n * 64 + f2];          // self term
    float acc0 = bf_lo(vs);
    float acc1 = bf_hi(vs);

    int beg = row_start[n];
    int end = beg + cnt[n];
    for (int e = beg; e < end; e += 4) {            // masked clamped unroll-4: no serial tail
        int last = end - 1;
        int e1 = e + 1 < end ? e + 1 : last;
        int e2 = e + 2 < end ? e + 2 : last;
        int e3 = e + 3 < end ? e + 3 : last;
        int s0 = col_src[e];
        int s1 = col_src[e1];
        int s2 = col_src[e2];
        int s3 = col_src[e3];
        uint32 v0 = Bs32[(size_t)s0 * 64 + f2];
        uint32 v1 = Bs32[(size_t)s1 * 64 + f2];
        uint32 v2 = Bs32[(size_t)s2 * 64 + f2];
        uint32 v3 = Bs32[(size_t)s3 * 64 + f2];
        float m1 = (e + 1 < end) ? 1.f : 0.f;
        float m2 = (e + 2 < end) ? 1.f : 0.f;
        float m3 = (e + 3 < end) ? 1.f : 0.f;
        acc0 += bf_lo(v0);           acc1 += bf_hi(v0);
        acc0 += m1 * bf_lo(v1);      acc1 += m1 * bf_hi(v1);
        acc0 += m2 * bf_lo(v2);      acc1 += m2 * bf_hi(v2);
        acc0 += m3 * bf_lo(v3);      acc1 += m3 * bf_hi(v3);
    }

    float di = dinv[n];
    float2 bcv = *(const float2*)(bc + f2 * 2);
    float o0 = acc0 * di + bcv.x;
    float o1 = acc1 * di + bcv.y;
    *(float2*)(C + (size_t)n * HID + f2 * 2) = make_float2(o0, o1);

    shs[ty][f2 * 2] = o0; shs[ty][f2 * 2 + 1] = o1;
    shq[ty][f2 * 2] = o0 * o0; shq[ty][f2 * 2 + 1] = o1 * o1;
    __syncthreads();
    int t = ty * 64 + f2;              // 0..255
    if (t < 128) {
        float s = shs[0][t] + shs[1][t] + shs[2][t] + shs[3][t];
        float q = shq[0][t] + shq[1][t] + shq[2][t] + shq[3][t];
        float* base = colsum_multi + (size_t)(blockIdx.x & 31) * 256;
        atomicAdd(&base[t], s);
        atomicAdd(&base[t + 128], q);
    }
}

// ---------------- BN finalize ----------------

__global__ void finalize_bn(const float* __restrict__ colsum_multi,   // [32][256]
                            const float* __restrict__ gamma, const float* __restrict__ beta,
                            float* __restrict__ scale, float* __restrict__ shift) {
    int f = threadIdx.x;
    float s = 0.f, q = 0.f;
    #pragma unroll
    for (int c = 0; c < 32; ++c) {
        s += colsum_multi[c * 256 + f];
        q += colsum_multi[c * 256 + f + 128];
    }
    float mu = s * (1.0f / N_NODES);
    float var = q * (1.0f / N_NODES) - mu * mu;
    float rstd = rsqrtf(var + BN_EPS);
    float sc = rstd * gamma[f];
    scale[f] = sc;
    shift[f] = beta[f] - mu * sc;
}

// ---------------- fused final BN-apply + output projection ----------------
// h3 = relu(C*sc+sh) + A (never materialized); out = h3 @ Wo + bo.
// block 256 -> 64 nodes: stage h3 into LDS, then 640 dot-products of length 128.

__global__ __launch_bounds__(256) void out_fused(const float* __restrict__ C,
                                                 const float* __restrict__ A,
                                                 const float* __restrict__ scale,
                                                 const float* __restrict__ shift,
                                                 const float* __restrict__ Wo,
                                                 const float* __restrict__ bo,
                                                 float* __restrict__ out) {
    __shared__ float Hs[64][132];          // pad 4: stride 132
    __shared__ float WoS[HID * OUT_DIM];
    __shared__ float scs[128], shs_[128];
    int tid = threadIdx.x;
    for (int i = tid; i < HID * OUT_DIM; i += 256) WoS[i] = Wo[i];
    if (tid < 128) { scs[tid] = scale[tid]; shs_[tid] = shift[tid]; }
    __syncthreads();

    int n0 = blockIdx.x * 64;
    #pragma unroll
    for (int i = 0; i < 8; ++i) {
        int lin = i * 256 + tid;           // 0..2047
        int row = lin >> 5;                // 0..63
        int colq = lin & 31;               // float4 index
        int n = n0 + row;
        float4 h = make_float4(0.f, 0.f, 0.f, 0.f);
        if (n < N_NODES) {
            float4 c = *(const float4*)(C + (size_t)n * HID + colq * 4);
            float4 s = *(const float4*)(scs + colq * 4);
            float4 t = *(const float4*)(shs_ + colq * 4);
            float4 a = *(const float4*)(A + (size_t)n * HID + colq * 4);
            h.x = fmaxf(c.x * s.x + t.x, 0.f) + a.x;
            h.y = fmaxf(c.y * s.y + t.y, 0.f) + a.y;
            h.z = fmaxf(c.z * s.z + t.z, 0.f) + a.z;
            h.w = fmaxf(c.w * s.w + t.w, 0.f) + a.w;
        }
        *(float4*)&Hs[row][colq * 4] = h;
    }
    __syncthreads();

    #pragma unroll
    for (int j = 0; j < 3; ++j) {
        int o = j * 256 + tid;             // 0..639
        if (o < 64 * OUT_DIM) {
            int nl = o / OUT_DIM;
            int c = o - nl * OUT_DIM;
            int n = n0 + nl;
            if (n < N_NODES) {
                float s = 0.f;
                #pragma unroll 4
                for (int k = 0; k < HID; ++k) s += Hs[nl][k] * WoS[k * OUT_DIM + c];
                out[(size_t)n * OUT_DIM + c] = s + bo[c];
            }
        }
    }
}

// ---------------- launch ----------------

extern "C" void kernel_launch(void* const* d_in, const int* in_sizes, int n_in,
                              void* d_out, int out_size, void* d_ws, size_t ws_size,
                              hipStream_t stream) {
    const float* x     = (const float*)d_in[0];
    const int*   ei    = (const int*)d_in[1];
    const int*   src   = ei;
    const int*   dst   = ei + N_EDGES;
    const float* W_in  = (const float*)d_in[2];
    const float* b_in  = (const float*)d_in[3];
    const float* Wc    = (const float*)d_in[4];
    const float* bc    = (const float*)d_in[5];
    const float* gamma = (const float*)d_in[6];
    const float* beta  = (const float*)d_in[7];
    const float* W_out = (const float*)d_in[8];
    const float* b_out = (const float*)d_in[9];
    float* out = (float*)d_out;

    char* p = (char*)d_ws;
    auto alloc = [&](size_t bytes) -> char* {
        char* q = p;
        p += (bytes + 255) & ~(size_t)255;
        return q;
    };
    float*  A         = (float*)alloc(sizeof(float) * N_NODES * HID);        // residual h (fp32)
    unsigned short* A16 = (unsigned short*)alloc(sizeof(unsigned short) * N_NODES * HID); // h0 bf16
    uint32* B16       = (uint32*)alloc(sizeof(unsigned short) * N_NODES * HID);           // messages bf16
    float*  C         = (float*)alloc(sizeof(float) * N_NODES * HID);        // aggregated
    float*  dinv      = (float*)alloc(sizeof(float) * N_NODES);
    int*    deg_cnt   = (int*)alloc(sizeof(int) * (N_NODES + 1));            // last int = cursor
    int*    cursor    = deg_cnt + N_NODES;
    int*    row_start = (int*)alloc(sizeof(int) * N_NODES);
    int*    fill_ptr  = (int*)alloc(sizeof(int) * N_NODES);
    int*    col_src   = (int*)alloc(sizeof(int) * N_EDGES);
    unsigned short* PWin = (unsigned short*)alloc(sizeof(unsigned short) * 4096 * 8);
    unsigned short* PWc  = (unsigned short*)alloc(sizeof(unsigned short) * 3 * 2048 * 8);
    float*  colsumAll = (float*)alloc(sizeof(float) * 3 * 32 * 256);         // 32 hashed copies per layer
    float*  scaleAll  = (float*)alloc(sizeof(float) * 3 * 128);
    float*  shiftAll  = (float*)alloc(sizeof(float) * 3 * 128);

    // CSR build
    hipMemsetAsync(deg_cnt, 0, sizeof(int) * (N_NODES + 1), stream);
    hipMemsetAsync(colsumAll, 0, sizeof(float) * 3 * 32 * 256, stream);
    count_kernel<<<(N_EDGES + 255) / 256, 256, 0, stream>>>(dst, deg_cnt);
    assign_kernel<<<(N_NODES + 255) / 256, 256, 0, stream>>>(deg_cnt, row_start, fill_ptr, dinv, cursor);
    fill_kernel<<<(N_EDGES + 255) / 256, 256, 0, stream>>>(src, dst, fill_ptr, col_src);

    // pack weights into MFMA B-fragment layout (bf16)
    pack_w_kernel<<<(4096 + 255) / 256, 256, 0, stream>>>(W_in, PWin, IN_DIM, 4096, 4096);
    pack_w_kernel<<<(3 * 2048 + 255) / 256, 256, 0, stream>>>(Wc, PWc, HID, 2048, 3 * 2048);

    const int gblk = (N_NODES + 63) / 64;

    // input projection + relu -> h0 bf16
    gemm_mfma<IN_DIM, 1, 0, 1, 1><<<gblk, 256, 0, stream>>>(
        x, PWin, b_in, nullptr, nullptr, nullptr, nullptr, A16, N_NODES);

    // layer 0 message gemm: B = (h0 @ Wc0) * dinv
    gemm_mfma<HID, 0, 0, 0, 1><<<gblk, 256, 0, stream>>>(
        A16, PWc, nullptr, dinv, nullptr, nullptr, nullptr, B16, N_NODES);

    for (int l = 0; l < 3; ++l) {
        float* colsum = colsumAll + (size_t)l * 32 * 256;
        float* scale = scaleAll + l * 128;
        float* shift = shiftAll + l * 128;
        agg_stats_kernel<<<N_NODES / 4, dim3(64, 4), 0, stream>>>(B16, dinv, row_start, deg_cnt, col_src,
                                                                  bc + l * HID, C, colsum);
        finalize_bn<<<1, 128, 0, stream>>>(colsum, gamma + l * HID, beta + l * HID, scale, shift);
        if (l == 0) {
            // fused: h1 = relu(BN(C0)) (no residual); write A; B = (h1 @ Wc1) * dinv
            gemm_mfma<HID, 2, 0, 0, 1><<<gblk, 256, 0, stream>>>(
                C, PWc + (size_t)1 * 2048 * 8, nullptr, dinv, scale, shift, A, B16, N_NODES);
        } else if (l == 1) {
            // fused: h2 = relu(BN(C1)) + h1; write A; B = (h2 @ Wc2) * dinv
            gemm_mfma<HID, 2, 1, 0, 1><<<gblk, 256, 0, stream>>>(
                C, PWc + (size_t)2 * 2048 * 8, nullptr, dinv, scale, shift, A, B16, N_NODES);
        } else {
            // fused final: h3 = relu(BN(C2)) + h2 (in LDS only); out = h3 @ Wo + bo
            out_fused<<<gblk, 256, 0, stream>>>(C, A, scale, shift, W_out, b_out, out);
        }
    }
}

// Round 10
// 369.248 us; speedup vs baseline: 1.6099x; 1.0542x over previous
//
#include <hip/hip_runtime.h>

#define N_NODES 50000
#define N_EDGES 600000
#define IN_DIM 256
#define HID 128
#define OUT_DIM 10
#define BN_EPS 1e-5f

typedef unsigned int uint32;
typedef __attribute__((ext_vector_type(8))) short short8;   // 8 bf16 = 4 VGPRs
typedef __attribute__((ext_vector_type(4))) float float4v;  // MFMA acc

__device__ __forceinline__ unsigned short f2bf_rne(float f) {
    uint32 u = __float_as_uint(f);
    u += 0x7FFF + ((u >> 16) & 1);          // round-to-nearest-even
    return (unsigned short)(u >> 16);
}
__device__ __forceinline__ float bf_lo(uint32 v) { return __uint_as_float(v << 16); }
__device__ __forceinline__ float bf_hi(uint32 v) { return __uint_as_float(v & 0xFFFF0000u); }
__device__ __forceinline__ float bfs(unsigned short s) { return __uint_as_float((uint32)s << 16); }

// ---------------- edge preprocessing: CSR by dst ----------------

__global__ void count_kernel(const int* __restrict__ dst, int* __restrict__ cnt) {
    int e = blockIdx.x * blockDim.x + threadIdx.x;
    if (e < N_EDGES) atomicAdd(&cnt[dst[e]], 1);
}

__global__ __launch_bounds__(256) void assign_kernel(const int* __restrict__ cnt,
                                                     int* __restrict__ row_start,
                                                     int* __restrict__ fill_ptr,
                                                     float* __restrict__ dinv,
                                                     int* __restrict__ cursor) {
    int i = blockIdx.x * blockDim.x + threadIdx.x;
    int c = (i < N_NODES) ? cnt[i] : 0;
    int lane = threadIdx.x & 63;
    int v = c;
    #pragma unroll
    for (int off = 1; off < 64; off <<= 1) {
        int t = __shfl_up(v, off, 64);
        if (lane >= off) v += t;
    }
    int waveTotal = __shfl(v, 63, 64);
    int base = 0;
    if (lane == 63) base = atomicAdd(cursor, waveTotal);
    base = __shfl(base, 63, 64);
    if (i < N_NODES) {
        int start = base + v - c;
        row_start[i] = start;
        fill_ptr[i] = start;
        dinv[i] = rsqrtf((float)c + 1.0f);   // +1 self-loop
    }
}

__global__ void fill_kernel(const int* __restrict__ src, const int* __restrict__ dst,
                            int* __restrict__ fill_ptr, int* __restrict__ col_src) {
    int e = blockIdx.x * blockDim.x + threadIdx.x;
    if (e < N_EDGES) {
        int d = dst[e];
        int p = atomicAdd(&fill_ptr[d], 1);
        col_src[p] = src[e];
    }
}

// ---------------- ALL weight packs in one dispatch ----------------
// MFMA B-frag layout: P[((kt*8+nt)*64+lane)*8+j] = bf16( W[kt*32+(lane>>4)*8+j][nt*16+(lane&15)] )
// idx < 4096: W_in (K=256) -> PWin.  idx >= 4096: Wc layer (K=128) -> PWc.

__global__ void pack_w_all(const float* __restrict__ W_in, const float* __restrict__ Wc,
                           unsigned short* __restrict__ PWin, unsigned short* __restrict__ PWc) {
    int idx = blockIdx.x * blockDim.x + threadIdx.x;
    if (idx >= 4096 + 3 * 2048) return;
    const float* W;
    unsigned short* P;
    int r;
    if (idx < 4096) { W = W_in; P = PWin + (size_t)idx * 8; r = idx; }
    else {
        int t = idx - 4096;
        int layer = t / 2048;
        r = t - layer * 2048;
        W = Wc + (size_t)layer * HID * HID;
        P = PWc + (size_t)(layer * 2048 + r) * 8;
    }
    int lane = r & 63;
    int nt = (r >> 6) & 7;
    int kt = r >> 9;
    int n = nt * 16 + (lane & 15);
    int kbase = kt * 32 + (lane >> 4) * 8;
    #pragma unroll
    for (int j = 0; j < 8; ++j) P[j] = f2bf_rne(W[(size_t)(kbase + j) * HID + n]);
}

// ---------------- fused input projection + layer-0 message GEMM ----------------
// h0 = relu(x@W_in + b_in) lives in regs/LDS only; B16 = (h0 @ Wc0) * dinv[row].
// MFMA mappings (m89-verified): A[m=lane&15][k=quad*8+j]; D: col=lane&15, row=quad*4+reg.

__global__ __launch_bounds__(256) void gemm_in_fused(const float* __restrict__ x,
                                                     const unsigned short* __restrict__ PWin,
                                                     const unsigned short* __restrict__ PWc0,
                                                     const float* __restrict__ b_in,
                                                     const float* __restrict__ dinv,
                                                     unsigned short* __restrict__ B16, int M) {
    __shared__ unsigned short As[64 * 40];     // x staging, stride 40 (2-way alias, free)
    __shared__ unsigned short Hs[64 * 136];    // h0 tile, stride 136 (bank offset 4/row)
    int tid = threadIdx.x;
    int w = tid >> 6, lane = tid & 63;
    int mrow = lane & 15, quad = lane >> 4;
    int m0 = blockIdx.x * 64;

    float4v acc[8];
    #pragma unroll
    for (int nt = 0; nt < 8; ++nt)
        #pragma unroll
        for (int i = 0; i < 4; ++i) acc[nt][i] = 0.f;

    int r = tid >> 2;        // staging row
    int cq = tid & 3;        // col quarter (8 floats)

    for (int kt = 0; kt < IN_DIM / 32; ++kt) {
        short8 pk;
        int row = m0 + r;
        if (row < M) {
            const float* srcp = x + (size_t)row * IN_DIM + kt * 32 + cq * 8;
            float4 a0 = *(const float4*)(srcp);
            float4 a1 = *(const float4*)(srcp + 4);
            pk[0] = (short)f2bf_rne(a0.x); pk[1] = (short)f2bf_rne(a0.y);
            pk[2] = (short)f2bf_rne(a0.z); pk[3] = (short)f2bf_rne(a0.w);
            pk[4] = (short)f2bf_rne(a1.x); pk[5] = (short)f2bf_rne(a1.y);
            pk[6] = (short)f2bf_rne(a1.z); pk[7] = (short)f2bf_rne(a1.w);
        } else {
            #pragma unroll
            for (int j = 0; j < 8; ++j) pk[j] = 0;
        }
        __syncthreads();
        *(short8*)&As[r * 40 + cq * 8] = pk;
        __syncthreads();

        short8 afrag = *(const short8*)&As[(w * 16 + mrow) * 40 + quad * 8];
        const unsigned short* pb = PWin + ((size_t)(kt * 8) * 64 + lane) * 8;
        #pragma unroll
        for (int nt = 0; nt < 8; ++nt) {
            short8 bfrag = *(const short8*)(pb + (size_t)nt * 64 * 8);
            acc[nt] = __builtin_amdgcn_mfma_f32_16x16x32_bf16(afrag, bfrag, acc[nt], 0, 0, 0);
        }
    }

    // epilogue-1: h0 = relu(acc + b_in) -> Hs (D-layout: row=w*16+quad*4+reg, col=nt*16+mrow)
    int rl = w * 16 + quad * 4;
    #pragma unroll
    for (int nt = 0; nt < 8; ++nt) {
        int col = nt * 16 + mrow;
        float bv = b_in[col];
        #pragma unroll
        for (int reg = 0; reg < 4; ++reg) {
            float h = fmaxf(acc[nt][reg] + bv, 0.f);
            Hs[(rl + reg) * 136 + col] = f2bf_rne(h);
        }
    }
    __syncthreads();

    // second GEMM: B = h0 @ Wc0 (K=128 from Hs)
    float4v acc2[8];
    #pragma unroll
    for (int nt = 0; nt < 8; ++nt)
        #pragma unroll
        for (int i = 0; i < 4; ++i) acc2[nt][i] = 0.f;

    #pragma unroll
    for (int kt = 0; kt < 4; ++kt) {
        short8 af2 = *(const short8*)&Hs[(w * 16 + mrow) * 136 + kt * 32 + quad * 8];
        const unsigned short* pb = PWc0 + ((size_t)(kt * 8) * 64 + lane) * 8;
        #pragma unroll
        for (int nt = 0; nt < 8; ++nt) {
            short8 bfrag = *(const short8*)(pb + (size_t)nt * 64 * 8);
            acc2[nt] = __builtin_amdgcn_mfma_f32_16x16x32_bf16(af2, bfrag, acc2[nt], 0, 0, 0);
        }
    }

    // epilogue-2: B16 = acc2 * dinv[row]
    int rowbase = m0 + w * 16 + quad * 4;
    float rs[4];
    #pragma unroll
    for (int reg = 0; reg < 4; ++reg) {
        int row = rowbase + reg;
        rs[reg] = (row < M) ? dinv[row] : 0.f;
    }
    #pragma unroll
    for (int nt = 0; nt < 8; ++nt) {
        int col = nt * 16 + mrow;
        #pragma unroll
        for (int reg = 0; reg < 4; ++reg) {
            int row = rowbase + reg;
            if (row < M) B16[(size_t)row * HID + col] = f2bf_rne(acc2[nt][reg] * rs[reg]);
        }
    }
}

// ---------------- fused CSR pull aggregation + BN column stats (C out = bf16) ----------------
// One node per wave, grid 12500 x (64,4); masked clamped unroll-4 (no serial tail).
// Stats: per-block LDS reduce -> atomicAdd into 32 hashed accumulator copies.

__global__ __launch_bounds__(256) void agg_stats_kernel(const uint32* __restrict__ Bs32,  // [N][64]
                                                        const float* __restrict__ dinv,
                                                        const int* __restrict__ row_start,
                                                        const int* __restrict__ cnt,
                                                        const int* __restrict__ col_src,
                                                        const float* __restrict__ bc,
                                                        uint32* __restrict__ C16,         // [N][64]
                                                        float* __restrict__ colsum_multi) { // [32][256]
    __shared__ float shs[4][128];
    __shared__ float shq[4][128];
    int f2 = threadIdx.x;              // 0..63
    int ty = threadIdx.y;              // 0..3
    int n = blockIdx.x * 4 + ty;       // N_NODES % 4 == 0

    uint32 vs = Bs32[(size_t)n * 64 + f2];          // self term
    float acc0 = bf_lo(vs);
    float acc1 = bf_hi(vs);

    int beg = row_start[n];
    int end = beg + cnt[n];
    for (int e = beg; e < end; e += 4) {
        int last = end - 1;
        int e1 = e + 1 < end ? e + 1 : last;
        int e2 = e + 2 < end ? e + 2 : last;
        int e3 = e + 3 < end ? e + 3 : last;
        int s0 = col_src[e];
        int s1 = col_src[e1];
        int s2 = col_src[e2];
        int s3 = col_src[e3];
        uint32 v0 = Bs32[(size_t)s0 * 64 + f2];
        uint32 v1 = Bs32[(size_t)s1 * 64 + f2];
        uint32 v2 = Bs32[(size_t)s2 * 64 + f2];
        uint32 v3 = Bs32[(size_t)s3 * 64 + f2];
        float m1 = (e + 1 < end) ? 1.f : 0.f;
        float m2 = (e + 2 < end) ? 1.f : 0.f;
        float m3 = (e + 3 < end) ? 1.f : 0.f;
        acc0 += bf_lo(v0);           acc1 += bf_hi(v0);
        acc0 += m1 * bf_lo(v1);      acc1 += m1 * bf_hi(v1);
        acc0 += m2 * bf_lo(v2);      acc1 += m2 * bf_hi(v2);
        acc0 += m3 * bf_lo(v3);      acc1 += m3 * bf_hi(v3);
    }

    float di = dinv[n];
    float2 bcv = *(const float2*)(bc + f2 * 2);
    float o0 = acc0 * di + bcv.x;
    float o1 = acc1 * di + bcv.y;
    C16[(size_t)n * 64 + f2] = (uint32)f2bf_rne(o0) | ((uint32)f2bf_rne(o1) << 16);

    shs[ty][f2 * 2] = o0; shs[ty][f2 * 2 + 1] = o1;
    shq[ty][f2 * 2] = o0 * o0; shq[ty][f2 * 2 + 1] = o1 * o1;
    __syncthreads();
    int t = ty * 64 + f2;              // 0..255
    if (t < 128) {
        float s = shs[0][t] + shs[1][t] + shs[2][t] + shs[3][t];
        float q = shq[0][t] + shq[1][t] + shq[2][t] + shq[3][t];
        float* base = colsum_multi + (size_t)(blockIdx.x & 31) * 256;
        atomicAdd(&base[t], s);
        atomicAdd(&base[t + 128], q);
    }
}

// ---------------- fused BN-finalize + BN-apply + residual + next message GEMM ----------------
// In-kernel finalize from colsum_multi; staging: h = relu(bf16(C)*sc+sh) (+A if RES);
// writes h -> A fp32 and bf16(h) -> LDS -> MFMA with next layer's Wc; B16 = (h@Wc)*dinv.

template <int RES>
__global__ __launch_bounds__(256) void gemm_bn_fused(const unsigned short* __restrict__ C16,
                                                     const unsigned short* __restrict__ PB,
                                                     const float* __restrict__ colsum_multi,
                                                     const float* __restrict__ gamma,
                                                     const float* __restrict__ beta,
                                                     const float* __restrict__ dinv,
                                                     float* __restrict__ A,
                                                     unsigned short* __restrict__ B16, int M) {
    __shared__ unsigned short As[64 * 40];
    __shared__ float scs[128], shb[128];
    int tid = threadIdx.x;
    int w = tid >> 6, lane = tid & 63;
    int mrow = lane & 15, quad = lane >> 4;
    int m0 = blockIdx.x * 64;

    if (tid < 128) {                       // in-block BN finalize
        float s = 0.f, q = 0.f;
        #pragma unroll
        for (int c = 0; c < 32; ++c) {
            s += colsum_multi[c * 256 + tid];
            q += colsum_multi[c * 256 + tid + 128];
        }
        float mu = s * (1.0f / N_NODES);
        float var = q * (1.0f / N_NODES) - mu * mu;
        float rstd = rsqrtf(var + BN_EPS);
        float sc = rstd * gamma[tid];
        scs[tid] = sc;
        shb[tid] = beta[tid] - mu * sc;
    }
    __syncthreads();

    float4v acc[8];
    #pragma unroll
    for (int nt = 0; nt < 8; ++nt)
        #pragma unroll
        for (int i = 0; i < 4; ++i) acc[nt][i] = 0.f;

    int r = tid >> 2;
    int cq = tid & 3;

    for (int kt = 0; kt < 4; ++kt) {
        short8 pk;
        int row = m0 + r;
        int col0 = kt * 32 + cq * 8;
        if (row < M) {
            short8 cv = *(const short8*)(C16 + (size_t)row * HID + col0);
            float h[8];
            #pragma unroll
            for (int j = 0; j < 8; ++j)
                h[j] = fmaxf(bfs((unsigned short)cv[j]) * scs[col0 + j] + shb[col0 + j], 0.f);
            float* ap = A + (size_t)row * HID + col0;
            if (RES) {
                float4 a0 = *(const float4*)(ap);
                float4 a1 = *(const float4*)(ap + 4);
                h[0] += a0.x; h[1] += a0.y; h[2] += a0.z; h[3] += a0.w;
                h[4] += a1.x; h[5] += a1.y; h[6] += a1.z; h[7] += a1.w;
            }
            *(float4*)(ap) = make_float4(h[0], h[1], h[2], h[3]);
            *(float4*)(ap + 4) = make_float4(h[4], h[5], h[6], h[7]);
            #pragma unroll
            for (int j = 0; j < 8; ++j) pk[j] = (short)f2bf_rne(h[j]);
        } else {
            #pragma unroll
            for (int j = 0; j < 8; ++j) pk[j] = 0;
        }
        __syncthreads();
        *(short8*)&As[r * 40 + cq * 8] = pk;
        __syncthreads();

        short8 afrag = *(const short8*)&As[(w * 16 + mrow) * 40 + quad * 8];
        const unsigned short* pb = PB + ((size_t)(kt * 8) * 64 + lane) * 8;
        #pragma unroll
        for (int nt = 0; nt < 8; ++nt) {
            short8 bfrag = *(const short8*)(pb + (size_t)nt * 64 * 8);
            acc[nt] = __builtin_amdgcn_mfma_f32_16x16x32_bf16(afrag, bfrag, acc[nt], 0, 0, 0);
        }
    }

    int rowbase = m0 + w * 16 + quad * 4;
    float rs[4];
    #pragma unroll
    for (int reg = 0; reg < 4; ++reg) {
        int row = rowbase + reg;
        rs[reg] = (row < M) ? dinv[row] : 0.f;
    }
    #pragma unroll
    for (int nt = 0; nt < 8; ++nt) {
        int col = nt * 16 + mrow;
        #pragma unroll
        for (int reg = 0; reg < 4; ++reg) {
            int row = rowbase + reg;
            if (row < M) B16[(size_t)row * HID + col] = f2bf_rne(acc[nt][reg] * rs[reg]);
        }
    }
}

// ---------------- fused final BN-finalize+apply + output projection ----------------
// h3 = relu(bf16(C)*sc+sh) + A (LDS only); out = h3 @ Wo + bo.

__global__ __launch_bounds__(256) void out_fused(const uint32* __restrict__ C16,  // [N][64]
                                                 const float* __restrict__ A,
                                                 const float* __restrict__ colsum_multi,
                                                 const float* __restrict__ gamma,
                                                 const float* __restrict__ beta,
                                                 const float* __restrict__ Wo,
                                                 const float* __restrict__ bo,
                                                 float* __restrict__ out) {
    __shared__ float Hs[64][132];          // pad 4
    __shared__ float WoS[HID * OUT_DIM];
    __shared__ float scs[128], shb[128];
    int tid = threadIdx.x;
    for (int i = tid; i < HID * OUT_DIM; i += 256) WoS[i] = Wo[i];
    if (tid < 128) {
        float s = 0.f, q = 0.f;
        #pragma unroll
        for (int c = 0; c < 32; ++c) {
            s += colsum_multi[c * 256 + tid];
            q += colsum_multi[c * 256 + tid + 128];
        }
        float mu = s * (1.0f / N_NODES);
        float var = q * (1.0f / N_NODES) - mu * mu;
        float rstd = rsqrtf(var + BN_EPS);
        float sc = rstd * gamma[tid];
        scs[tid] = sc;
        shb[tid] = beta[tid] - mu * sc;
    }
    __syncthreads();

    int n0 = blockIdx.x * 64;
    #pragma unroll
    for (int i = 0; i < 8; ++i) {
        int lin = i * 256 + tid;           // 0..2047
        int row = lin >> 5;                // 0..63
        int colq = lin & 31;               // float4 group
        int n = n0 + row;
        float4 h = make_float4(0.f, 0.f, 0.f, 0.f);
        if (n < N_NODES) {
            uint2 cv = ((const uint2*)C16)[(size_t)n * 32 + colq];
            float c0 = bf_lo(cv.x), c1 = bf_hi(cv.x), c2 = bf_lo(cv.y), c3 = bf_hi(cv.y);
            float4 s = *(const float4*)(scs + colq * 4);
            float4 t = *(const float4*)(shb + colq * 4);
            float4 a = *(const float4*)(A + (size_t)n * HID + colq * 4);
            h.x = fmaxf(c0 * s.x + t.x, 0.f) + a.x;
            h.y = fmaxf(c1 * s.y + t.y, 0.f) + a.y;
            h.z = fmaxf(c2 * s.z + t.z, 0.f) + a.z;
            h.w = fmaxf(c3 * s.w + t.w, 0.f) + a.w;
        }
        *(float4*)&Hs[row][colq * 4] = h;
    }
    __syncthreads();

    #pragma unroll
    for (int j = 0; j < 3; ++j) {
        int o = j * 256 + tid;             // 0..639
        if (o < 64 * OUT_DIM) {
            int nl = o / OUT_DIM;
            int c = o - nl * OUT_DIM;
            int n = n0 + nl;
            if (n < N_NODES) {
                float s = 0.f;
                #pragma unroll 4
                for (int k = 0; k < HID; ++k) s += Hs[nl][k] * WoS[k * OUT_DIM + c];
                out[(size_t)n * OUT_DIM + c] = s + bo[c];
            }
        }
    }
}

// ---------------- launch ----------------

extern "C" void kernel_launch(void* const* d_in, const int* in_sizes, int n_in,
                              void* d_out, int out_size, void* d_ws, size_t ws_size,
                              hipStream_t stream) {
    const float* x     = (const float*)d_in[0];
    const int*   ei    = (const int*)d_in[1];
    const int*   src   = ei;
    const int*   dst   = ei + N_EDGES;
    const float* W_in  = (const float*)d_in[2];
    const float* b_in  = (const float*)d_in[3];
    const float* Wc    = (const float*)d_in[4];
    const float* bc    = (const float*)d_in[5];
    const float* gamma = (const float*)d_in[6];
    const float* beta  = (const float*)d_in[7];
    const float* W_out = (const float*)d_in[8];
    const float* b_out = (const float*)d_in[9];
    float* out = (float*)d_out;

    char* p = (char*)d_ws;
    auto alloc = [&](size_t bytes) -> char* {
        char* q = p;
        p += (bytes + 255) & ~(size_t)255;
        return q;
    };
    float*  A         = (float*)alloc(sizeof(float) * N_NODES * HID);        // residual h (fp32)
    unsigned short* B16 = (unsigned short*)alloc(sizeof(unsigned short) * N_NODES * HID); // messages bf16
    uint32* C16       = (uint32*)alloc(sizeof(unsigned short) * N_NODES * HID);           // aggregated bf16
    float*  dinv      = (float*)alloc(sizeof(float) * N_NODES);
    int*    deg_cnt   = (int*)alloc(sizeof(int) * (N_NODES + 1));            // last int = cursor
    int*    cursor    = deg_cnt + N_NODES;
    int*    row_start = (int*)alloc(sizeof(int) * N_NODES);
    int*    fill_ptr  = (int*)alloc(sizeof(int) * N_NODES);
    int*    col_src   = (int*)alloc(sizeof(int) * N_EDGES);
    unsigned short* PWin = (unsigned short*)alloc(sizeof(unsigned short) * 4096 * 8);
    unsigned short* PWc  = (unsigned short*)alloc(sizeof(unsigned short) * 3 * 2048 * 8);
    float*  colsumAll = (float*)alloc(sizeof(float) * 3 * 32 * 256);         // 32 hashed copies per layer

    // CSR build
    hipMemsetAsync(deg_cnt, 0, sizeof(int) * (N_NODES + 1), stream);
    hipMemsetAsync(colsumAll, 0, sizeof(float) * 3 * 32 * 256, stream);
    count_kernel<<<(N_EDGES + 255) / 256, 256, 0, stream>>>(dst, deg_cnt);
    assign_kernel<<<(N_NODES + 255) / 256, 256, 0, stream>>>(deg_cnt, row_start, fill_ptr, dinv, cursor);
    fill_kernel<<<(N_EDGES + 255) / 256, 256, 0, stream>>>(src, dst, fill_ptr, col_src);

    // all weight packs (W_in + 3x Wc), one dispatch
    pack_w_all<<<(4096 + 3 * 2048 + 255) / 256, 256, 0, stream>>>(W_in, Wc, PWin, PWc);

    const int gblk = (N_NODES + 63) / 64;

    // fused input projection + layer-0 message gemm: B0 = (relu(x@W_in+b) @ Wc0) * dinv
    gemm_in_fused<<<gblk, 256, 0, stream>>>(x, PWin, PWc, b_in, dinv, B16, N_NODES);

    for (int l = 0; l < 3; ++l) {
        float* colsum = colsumAll + (size_t)l * 32 * 256;
        agg_stats_kernel<<<N_NODES / 4, dim3(64, 4), 0, stream>>>(
            (const uint32*)B16, dinv, row_start, deg_cnt, col_src, bc + l * HID, C16, colsum);
        if (l == 0) {
            gemm_bn_fused<0><<<gblk, 256, 0, stream>>>(
                (const unsigned short*)C16, PWc + (size_t)1 * 2048 * 8, colsum,
                gamma, beta, dinv, A, B16, N_NODES);
        } else if (l == 1) {
            gemm_bn_fused<1><<<gblk, 256, 0, stream>>>(
                (const unsigned short*)C16, PWc + (size_t)2 * 2048 * 8, colsum,
                gamma + HID, beta + HID, dinv, A, B16, N_NODES);
        } else {
            out_fused<<<gblk, 256, 0, stream>>>(
                C16, A, colsum, gamma + 2 * HID, beta + 2 * HID, W_out, b_out, out);
        }
    }
}

// Round 11
// 346.816 us; speedup vs baseline: 1.7141x; 1.0647x over previous
//
#include <hip/hip_runtime.h>

#define N_NODES 50000
#define N_EDGES 600000
#define IN_DIM 256
#define HID 128
#define OUT_DIM 10
#define BN_EPS 1e-5f

typedef unsigned int uint32;
typedef unsigned short ushort_t;
typedef __attribute__((ext_vector_type(8))) short short8;   // 8 bf16 = 4 VGPRs
typedef __attribute__((ext_vector_type(4))) float float4v;  // MFMA acc

__device__ __forceinline__ unsigned short f2bf_rne(float f) {
    uint32 u = __float_as_uint(f);
    u += 0x7FFF + ((u >> 16) & 1);          // round-to-nearest-even
    return (unsigned short)(u >> 16);
}
__device__ __forceinline__ float bf_lo(uint32 v) { return __uint_as_float(v << 16); }
__device__ __forceinline__ float bf_hi(uint32 v) { return __uint_as_float(v & 0xFFFF0000u); }
__device__ __forceinline__ float bfs(unsigned short s) { return __uint_as_float((uint32)s << 16); }

// ---------------- edge preprocessing: CSR by dst ----------------

__global__ void count_kernel(const int* __restrict__ dst, int* __restrict__ cnt) {
    int e = blockIdx.x * blockDim.x + threadIdx.x;
    if (e < N_EDGES) atomicAdd(&cnt[dst[e]], 1);
}

__global__ __launch_bounds__(256) void assign_kernel(const int* __restrict__ cnt,
                                                     int* __restrict__ row_start,
                                                     int* __restrict__ fill_ptr,
                                                     float* __restrict__ dinv,
                                                     int* __restrict__ cursor) {
    int i = blockIdx.x * blockDim.x + threadIdx.x;
    int c = (i < N_NODES) ? cnt[i] : 0;
    int lane = threadIdx.x & 63;
    int v = c;
    #pragma unroll
    for (int off = 1; off < 64; off <<= 1) {
        int t = __shfl_up(v, off, 64);
        if (lane >= off) v += t;
    }
    int waveTotal = __shfl(v, 63, 64);
    int base = 0;
    if (lane == 63) base = atomicAdd(cursor, waveTotal);
    base = __shfl(base, 63, 64);
    if (i < N_NODES) {
        int start = base + v - c;
        row_start[i] = start;
        fill_ptr[i] = start;
        dinv[i] = rsqrtf((float)c + 1.0f);   // +1 self-loop
    }
}

__global__ void fill_kernel(const int* __restrict__ src, const int* __restrict__ dst,
                            int* __restrict__ fill_ptr, ushort_t* __restrict__ col_src) {
    int e = blockIdx.x * blockDim.x + threadIdx.x;
    if (e < N_EDGES) {
        int d = dst[e];
        int p = atomicAdd(&fill_ptr[d], 1);
        col_src[p] = (ushort_t)src[e];      // src < 50000 < 65536
    }
}

// ---------------- ALL weight packs in one dispatch ----------------
// MFMA B-frag layout: P[((kt*8+nt)*64+lane)*8+j] = bf16( W[kt*32+(lane>>4)*8+j][nt*16+(lane&15)] )

__global__ void pack_w_all(const float* __restrict__ W_in, const float* __restrict__ Wc,
                           unsigned short* __restrict__ PWin, unsigned short* __restrict__ PWc) {
    int idx = blockIdx.x * blockDim.x + threadIdx.x;
    if (idx >= 4096 + 3 * 2048) return;
    const float* W;
    unsigned short* P;
    int r;
    if (idx < 4096) { W = W_in; P = PWin + (size_t)idx * 8; r = idx; }
    else {
        int t = idx - 4096;
        int layer = t / 2048;
        r = t - layer * 2048;
        W = Wc + (size_t)layer * HID * HID;
        P = PWc + (size_t)(layer * 2048 + r) * 8;
    }
    int lane = r & 63;
    int nt = (r >> 6) & 7;
    int kt = r >> 9;
    int n = nt * 16 + (lane & 15);
    int kbase = kt * 32 + (lane >> 4) * 8;
    #pragma unroll
    for (int j = 0; j < 8; ++j) P[j] = f2bf_rne(W[(size_t)(kbase + j) * HID + n]);
}

// ---------------- fused input projection + layer-0 message GEMM ----------------
// h0 = relu(x@W_in + b_in) in regs/LDS only; B16 = (h0 @ Wc0) * dinv[row].
// MFMA mappings (m89-verified): A[m=lane&15][k=quad*8+j]; D: col=lane&15, row=quad*4+reg.

__global__ __launch_bounds__(256) void gemm_in_fused(const float* __restrict__ x,
                                                     const unsigned short* __restrict__ PWin,
                                                     const unsigned short* __restrict__ PWc0,
                                                     const float* __restrict__ b_in,
                                                     const float* __restrict__ dinv,
                                                     unsigned short* __restrict__ B16, int M) {
    __shared__ unsigned short As[64 * 40];     // x staging, stride 40 (2-way alias, free)
    __shared__ unsigned short Hs[64 * 136];    // h0 tile
    int tid = threadIdx.x;
    int w = tid >> 6, lane = tid & 63;
    int mrow = lane & 15, quad = lane >> 4;
    int m0 = blockIdx.x * 64;

    float4v acc[8];
    #pragma unroll
    for (int nt = 0; nt < 8; ++nt)
        #pragma unroll
        for (int i = 0; i < 4; ++i) acc[nt][i] = 0.f;

    int r = tid >> 2;        // staging row
    int cq = tid & 3;        // col quarter (8 floats)

    for (int kt = 0; kt < IN_DIM / 32; ++kt) {
        short8 pk;
        int row = m0 + r;
        if (row < M) {
            const float* srcp = x + (size_t)row * IN_DIM + kt * 32 + cq * 8;
            float4 a0 = *(const float4*)(srcp);
            float4 a1 = *(const float4*)(srcp + 4);
            pk[0] = (short)f2bf_rne(a0.x); pk[1] = (short)f2bf_rne(a0.y);
            pk[2] = (short)f2bf_rne(a0.z); pk[3] = (short)f2bf_rne(a0.w);
            pk[4] = (short)f2bf_rne(a1.x); pk[5] = (short)f2bf_rne(a1.y);
            pk[6] = (short)f2bf_rne(a1.z); pk[7] = (short)f2bf_rne(a1.w);
        } else {
            #pragma unroll
            for (int j = 0; j < 8; ++j) pk[j] = 0;
        }
        __syncthreads();
        *(short8*)&As[r * 40 + cq * 8] = pk;
        __syncthreads();

        short8 afrag = *(const short8*)&As[(w * 16 + mrow) * 40 + quad * 8];
        const unsigned short* pb = PWin + ((size_t)(kt * 8) * 64 + lane) * 8;
        #pragma unroll
        for (int nt = 0; nt < 8; ++nt) {
            short8 bfrag = *(const short8*)(pb + (size_t)nt * 64 * 8);
            acc[nt] = __builtin_amdgcn_mfma_f32_16x16x32_bf16(afrag, bfrag, acc[nt], 0, 0, 0);
        }
    }

    // epilogue-1: h0 = relu(acc + b_in) -> Hs (D-layout: row=w*16+quad*4+reg, col=nt*16+mrow)
    int rl = w * 16 + quad * 4;
    #pragma unroll
    for (int nt = 0; nt < 8; ++nt) {
        int col = nt * 16 + mrow;
        float bv = b_in[col];
        #pragma unroll
        for (int reg = 0; reg < 4; ++reg) {
            float h = fmaxf(acc[nt][reg] + bv, 0.f);
            Hs[(rl + reg) * 136 + col] = f2bf_rne(h);
        }
    }
    __syncthreads();

    // second GEMM: B = h0 @ Wc0 (K=128 from Hs)
    float4v acc2[8];
    #pragma unroll
    for (int nt = 0; nt < 8; ++nt)
        #pragma unroll
        for (int i = 0; i < 4; ++i) acc2[nt][i] = 0.f;

    #pragma unroll
    for (int kt = 0; kt < 4; ++kt) {
        short8 af2 = *(const short8*)&Hs[(w * 16 + mrow) * 136 + kt * 32 + quad * 8];
        const unsigned short* pb = PWc0 + ((size_t)(kt * 8) * 64 + lane) * 8;
        #pragma unroll
        for (int nt = 0; nt < 8; ++nt) {
            short8 bfrag = *(const short8*)(pb + (size_t)nt * 64 * 8);
            acc2[nt] = __builtin_amdgcn_mfma_f32_16x16x32_bf16(af2, bfrag, acc2[nt], 0, 0, 0);
        }
    }

    // epilogue-2: B16 = acc2 * dinv[row]
    int rowbase = m0 + w * 16 + quad * 4;
    float rs[4];
    #pragma unroll
    for (int reg = 0; reg < 4; ++reg) {
        int row = rowbase + reg;
        rs[reg] = (row < M) ? dinv[row] : 0.f;
    }
    #pragma unroll
    for (int nt = 0; nt < 8; ++nt) {
        int col = nt * 16 + mrow;
        #pragma unroll
        for (int reg = 0; reg < 4; ++reg) {
            int row = rowbase + reg;
            if (row < M) B16[(size_t)row * HID + col] = f2bf_rne(acc2[nt][reg] * rs[reg]);
        }
    }
}

// ---------------- fused CSR pull aggregation + BN column stats (C out = bf16) ----------------
// One node per wave, grid 12500 x (64,4); masked clamped unroll-8 (8 gathers in flight,
// clamp duplicates hit the same L1 line). Stats: LDS reduce -> 32 hashed global accumulators.

__global__ __launch_bounds__(256) void agg_stats_kernel(const uint32* __restrict__ Bs32,  // [N][64]
                                                        const float* __restrict__ dinv,
                                                        const int* __restrict__ row_start,
                                                        const int* __restrict__ cnt,
                                                        const ushort_t* __restrict__ col_src,
                                                        const float* __restrict__ bc,
                                                        uint32* __restrict__ C16,         // [N][64]
                                                        float* __restrict__ colsum_multi) { // [32][256]
    __shared__ float shs[4][128];
    __shared__ float shq[4][128];
    int f2 = threadIdx.x;              // 0..63
    int ty = threadIdx.y;              // 0..3
    int n = blockIdx.x * 4 + ty;       // N_NODES % 4 == 0

    uint32 vs = Bs32[(size_t)n * 64 + f2];          // self term
    float acc0 = bf_lo(vs);
    float acc1 = bf_hi(vs);

    int beg = row_start[n];
    int end = beg + cnt[n];
    for (int e = beg; e < end; e += 8) {
        int last = end - 1;
        int idx[8];
        #pragma unroll
        for (int k = 0; k < 8; ++k) idx[k] = (e + k < end) ? (e + k) : last;
        int s[8];
        #pragma unroll
        for (int k = 0; k < 8; ++k) s[k] = col_src[idx[k]];
        uint32 v[8];
        #pragma unroll
        for (int k = 0; k < 8; ++k) v[k] = Bs32[(size_t)s[k] * 64 + f2];
        acc0 += bf_lo(v[0]); acc1 += bf_hi(v[0]);
        #pragma unroll
        for (int k = 1; k < 8; ++k) {
            float m = (e + k < end) ? 1.f : 0.f;
            acc0 += m * bf_lo(v[k]);
            acc1 += m * bf_hi(v[k]);
        }
    }

    float di = dinv[n];
    float2 bcv = *(const float2*)(bc + f2 * 2);
    float o0 = acc0 * di + bcv.x;
    float o1 = acc1 * di + bcv.y;
    C16[(size_t)n * 64 + f2] = (uint32)f2bf_rne(o0) | ((uint32)f2bf_rne(o1) << 16);

    shs[ty][f2 * 2] = o0; shs[ty][f2 * 2 + 1] = o1;
    shq[ty][f2 * 2] = o0 * o0; shq[ty][f2 * 2 + 1] = o1 * o1;
    __syncthreads();
    int t = ty * 64 + f2;              // 0..255
    if (t < 128) {
        float s = shs[0][t] + shs[1][t] + shs[2][t] + shs[3][t];
        float q = shq[0][t] + shq[1][t] + shq[2][t] + shq[3][t];
        float* base = colsum_multi + (size_t)(blockIdx.x & 31) * 256;
        atomicAdd(&base[t], s);
        atomicAdd(&base[t + 128], q);
    }
}

// ---------------- fused BN-finalize + BN-apply + residual + next message GEMM ----------------
// In-kernel finalize; staging: h = relu(bf16(C)*sc+sh) (+A16 if RES);
// writes bf16(h) -> A16 and -> LDS -> MFMA with next layer's Wc; B16 = (h@Wc)*dinv.

template <int RES>
__global__ __launch_bounds__(256) void gemm_bn_fused(const unsigned short* __restrict__ C16,
                                                     const unsigned short* __restrict__ PB,
                                                     const float* __restrict__ colsum_multi,
                                                     const float* __restrict__ gamma,
                                                     const float* __restrict__ beta,
                                                     const float* __restrict__ dinv,
                                                     unsigned short* __restrict__ A16,
                                                     unsigned short* __restrict__ B16, int M) {
    __shared__ unsigned short As[64 * 40];
    __shared__ float scs[128], shb[128];
    int tid = threadIdx.x;
    int w = tid >> 6, lane = tid & 63;
    int mrow = lane & 15, quad = lane >> 4;
    int m0 = blockIdx.x * 64;

    if (tid < 128) {                       // in-block BN finalize
        float s = 0.f, q = 0.f;
        #pragma unroll
        for (int c = 0; c < 32; ++c) {
            s += colsum_multi[c * 256 + tid];
            q += colsum_multi[c * 256 + tid + 128];
        }
        float mu = s * (1.0f / N_NODES);
        float var = q * (1.0f / N_NODES) - mu * mu;
        float rstd = rsqrtf(var + BN_EPS);
        float sc = rstd * gamma[tid];
        scs[tid] = sc;
        shb[tid] = beta[tid] - mu * sc;
    }
    __syncthreads();

    float4v acc[8];
    #pragma unroll
    for (int nt = 0; nt < 8; ++nt)
        #pragma unroll
        for (int i = 0; i < 4; ++i) acc[nt][i] = 0.f;

    int r = tid >> 2;
    int cq = tid & 3;

    for (int kt = 0; kt < 4; ++kt) {
        short8 pk;
        int row = m0 + r;
        int col0 = kt * 32 + cq * 8;
        if (row < M) {
            short8 cv = *(const short8*)(C16 + (size_t)row * HID + col0);
            float h[8];
            #pragma unroll
            for (int j = 0; j < 8; ++j)
                h[j] = fmaxf(bfs((unsigned short)cv[j]) * scs[col0 + j] + shb[col0 + j], 0.f);
            unsigned short* ap = A16 + (size_t)row * HID + col0;
            if (RES) {
                short8 av = *(const short8*)(ap);
                #pragma unroll
                for (int j = 0; j < 8; ++j) h[j] += bfs((unsigned short)av[j]);
            }
            #pragma unroll
            for (int j = 0; j < 8; ++j) pk[j] = (short)f2bf_rne(h[j]);
            *(short8*)(ap) = pk;
        } else {
            #pragma unroll
            for (int j = 0; j < 8; ++j) pk[j] = 0;
        }
        __syncthreads();
        *(short8*)&As[r * 40 + cq * 8] = pk;
        __syncthreads();

        short8 afrag = *(const short8*)&As[(w * 16 + mrow) * 40 + quad * 8];
        const unsigned short* pb = PB + ((size_t)(kt * 8) * 64 + lane) * 8;
        #pragma unroll
        for (int nt = 0; nt < 8; ++nt) {
            short8 bfrag = *(const short8*)(pb + (size_t)nt * 64 * 8);
            acc[nt] = __builtin_amdgcn_mfma_f32_16x16x32_bf16(afrag, bfrag, acc[nt], 0, 0, 0);
        }
    }

    int rowbase = m0 + w * 16 + quad * 4;
    float rs[4];
    #pragma unroll
    for (int reg = 0; reg < 4; ++reg) {
        int row = rowbase + reg;
        rs[reg] = (row < M) ? dinv[row] : 0.f;
    }
    #pragma unroll
    for (int nt = 0; nt < 8; ++nt) {
        int col = nt * 16 + mrow;
        #pragma unroll
        for (int reg = 0; reg < 4; ++reg) {
            int row = rowbase + reg;
            if (row < M) B16[(size_t)row * HID + col] = f2bf_rne(acc[nt][reg] * rs[reg]);
        }
    }
}

// ---------------- fused final BN-finalize+apply + output projection ----------------
// h3 = relu(bf16(C)*sc+sh) + A16 (LDS only); out = h3 @ Wo + bo.

__global__ __launch_bounds__(256) void out_fused(const uint32* __restrict__ C16,  // [N][64]
                                                 const uint32* __restrict__ A16,  // [N][64]
                                                 const float* __restrict__ colsum_multi,
                                                 const float* __restrict__ gamma,
                                                 const float* __restrict__ beta,
                                                 const float* __restrict__ Wo,
                                                 const float* __restrict__ bo,
                                                 float* __restrict__ out) {
    __shared__ float Hs[64][132];          // pad 4
    __shared__ float WoS[HID * OUT_DIM];
    __shared__ float scs[128], shb[128];
    int tid = threadIdx.x;
    for (int i = tid; i < HID * OUT_DIM; i += 256) WoS[i] = Wo[i];
    if (tid < 128) {
        float s = 0.f, q = 0.f;
        #pragma unroll
        for (int c = 0; c < 32; ++c) {
            s += colsum_multi[c * 256 + tid];
            q += colsum_multi[c * 256 + tid + 128];
        }
        float mu = s * (1.0f / N_NODES);
        float var = q * (1.0f / N_NODES) - mu * mu;
        float rstd = rsqrtf(var + BN_EPS);
        float sc = rstd * gamma[tid];
        scs[tid] = sc;
        shb[tid] = beta[tid] - mu * sc;
    }
    __syncthreads();

    int n0 = blockIdx.x * 64;
    #pragma unroll
    for (int i = 0; i < 8; ++i) {
        int lin = i * 256 + tid;           // 0..2047
        int row = lin >> 5;                // 0..63
        int colq = lin & 31;               // 4-feature group
        int n = n0 + row;
        float4 h = make_float4(0.f, 0.f, 0.f, 0.f);
        if (n < N_NODES) {
            uint2 cv = ((const uint2*)C16)[(size_t)n * 32 + colq];
            uint2 av = ((const uint2*)A16)[(size_t)n * 32 + colq];
            float c0 = bf_lo(cv.x), c1 = bf_hi(cv.x), c2 = bf_lo(cv.y), c3 = bf_hi(cv.y);
            float4 s = *(const float4*)(scs + colq * 4);
            float4 t = *(const float4*)(shb + colq * 4);
            h.x = fmaxf(c0 * s.x + t.x, 0.f) + bf_lo(av.x);
            h.y = fmaxf(c1 * s.y + t.y, 0.f) + bf_hi(av.x);
            h.z = fmaxf(c2 * s.z + t.z, 0.f) + bf_lo(av.y);
            h.w = fmaxf(c3 * s.w + t.w, 0.f) + bf_hi(av.y);
        }
        *(float4*)&Hs[row][colq * 4] = h;
    }
    __syncthreads();

    #pragma unroll
    for (int j = 0; j < 3; ++j) {
        int o = j * 256 + tid;             // 0..639
        if (o < 64 * OUT_DIM) {
            int nl = o / OUT_DIM;
            int c = o - nl * OUT_DIM;
            int n = n0 + nl;
            if (n < N_NODES) {
                float s = 0.f;
                #pragma unroll 4
                for (int k = 0; k < HID; ++k) s += Hs[nl][k] * WoS[k * OUT_DIM + c];
                out[(size_t)n * OUT_DIM + c] = s + bo[c];
            }
        }
    }
}

// ---------------- launch ----------------

extern "C" void kernel_launch(void* const* d_in, const int* in_sizes, int n_in,
                              void* d_out, int out_size, void* d_ws, size_t ws_size,
                              hipStream_t stream) {
    const float* x     = (const float*)d_in[0];
    const int*   ei    = (const int*)d_in[1];
    const int*   src   = ei;
    const int*   dst   = ei + N_EDGES;
    const float* W_in  = (const float*)d_in[2];
    const float* b_in  = (const float*)d_in[3];
    const float* Wc    = (const float*)d_in[4];
    const float* bc    = (const float*)d_in[5];
    const float* gamma = (const float*)d_in[6];
    const float* beta  = (const float*)d_in[7];
    const float* W_out = (const float*)d_in[8];
    const float* b_out = (const float*)d_in[9];
    float* out = (float*)d_out;

    char* p = (char*)d_ws;
    auto alloc = [&](size_t bytes) -> char* {
        char* q = p;
        p += (bytes + 255) & ~(size_t)255;
        return q;
    };
    unsigned short* A16 = (unsigned short*)alloc(sizeof(unsigned short) * N_NODES * HID); // residual h bf16
    unsigned short* B16 = (unsigned short*)alloc(sizeof(unsigned short) * N_NODES * HID); // messages bf16
    uint32* C16       = (uint32*)alloc(sizeof(unsigned short) * N_NODES * HID);           // aggregated bf16
    float*  dinv      = (float*)alloc(sizeof(float) * N_NODES);
    int*    deg_cnt   = (int*)alloc(sizeof(int) * (N_NODES + 1));            // last int = cursor
    int*    cursor    = deg_cnt + N_NODES;
    int*    row_start = (int*)alloc(sizeof(int) * N_NODES);
    int*    fill_ptr  = (int*)alloc(sizeof(int) * N_NODES);
    ushort_t* col_src = (ushort_t*)alloc(sizeof(ushort_t) * N_EDGES);
    unsigned short* PWin = (unsigned short*)alloc(sizeof(unsigned short) * 4096 * 8);
    unsigned short* PWc  = (unsigned short*)alloc(sizeof(unsigned short) * 3 * 2048 * 8);
    float*  colsumAll = (float*)alloc(sizeof(float) * 3 * 32 * 256);         // 32 hashed copies per layer

    // CSR build
    hipMemsetAsync(deg_cnt, 0, sizeof(int) * (N_NODES + 1), stream);
    hipMemsetAsync(colsumAll, 0, sizeof(float) * 3 * 32 * 256, stream);
    count_kernel<<<(N_EDGES + 255) / 256, 256, 0, stream>>>(dst, deg_cnt);
    assign_kernel<<<(N_NODES + 255) / 256, 256, 0, stream>>>(deg_cnt, row_start, fill_ptr, dinv, cursor);
    fill_kernel<<<(N_EDGES + 255) / 256, 256, 0, stream>>>(src, dst, fill_ptr, col_src);

    // all weight packs (W_in + 3x Wc), one dispatch
    pack_w_all<<<(4096 + 3 * 2048 + 255) / 256, 256, 0, stream>>>(W_in, Wc, PWin, PWc);

    const int gblk = (N_NODES + 63) / 64;

    // fused input projection + layer-0 message gemm: B0 = (relu(x@W_in+b) @ Wc0) * dinv
    gemm_in_fused<<<gblk, 256, 0, stream>>>(x, PWin, PWc, b_in, dinv, B16, N_NODES);

    for (int l = 0; l < 3; ++l) {
        float* colsum = colsumAll + (size_t)l * 32 * 256;
        agg_stats_kernel<<<N_NODES / 4, dim3(64, 4), 0, stream>>>(
            (const uint32*)B16, dinv, row_start, deg_cnt, col_src, bc + l * HID, C16, colsum);
        if (l == 0) {
            gemm_bn_fused<0><<<gblk, 256, 0, stream>>>(
                (const unsigned short*)C16, PWc + (size_t)1 * 2048 * 8, colsum,
                gamma, beta, dinv, A16, B16, N_NODES);
        } else if (l == 1) {
            gemm_bn_fused<1><<<gblk, 256, 0, stream>>>(
                (const unsigned short*)C16, PWc + (size_t)2 * 2048 * 8, colsum,
                gamma + HID, beta + HID, dinv, A16, B16, N_NODES);
        } else {
            out_fused<<<gblk, 256, 0, stream>>>(
                C16, (const uint32*)A16, colsum, gamma + 2 * HID, beta + 2 * HID, W_out, b_out, out);
        }
    }
}